// Round 12
// baseline (389.371 us; speedup 1.0000x reference)
//
#include <hip/hip_runtime.h>
#include <hip/hip_bf16.h>
#include <math.h>

#define NTOK 16384
#define HDIM 1024
#define DSZ 32
#define DGZ 32
#define FMZ 64
#define NEXP 4
#define FFZ 2048

typedef __attribute__((ext_vector_type(4))) float f32x4;
typedef __attribute__((ext_vector_type(8))) short bf16x8;

__device__ __forceinline__ unsigned short f2bf(float f){
    union { float f; unsigned int u; } v; v.f = f;
    unsigned int r = (v.u + 0x7FFFu + ((v.u >> 16) & 1u)) >> 16;
    return (unsigned short)r;
}
__device__ __forceinline__ float gelu_f(float x){
    return 0.5f * x * (1.0f + erff(x * 0.70710678118654752440f));
}
__device__ __forceinline__ void gld_lds16(const void* g, void* s){
    __builtin_amdgcn_global_load_lds((const __attribute__((address_space(1))) unsigned int*)g,
                                     (__attribute__((address_space(3))) unsigned int*)s, 16, 0, 0);
}

// ---------------- kernel 1: per-token LN stats only ----------------
__global__ __launch_bounds__(256) void k_stats(const float* __restrict__ h,
        float* __restrict__ mu_g, float* __restrict__ rs_g){
    int tid = threadIdx.x;
    int wv = tid >> 6, l = tid & 63;
    int tok = blockIdx.x * 4 + wv;
    const float4* hp = (const float4*)(h + (size_t)tok * HDIM);
    float s = 0.f, s2 = 0.f;
    #pragma unroll
    for (int p = 0; p < 4; ++p){
        float4 v = hp[p * 64 + l];
        s  += v.x + v.y + v.z + v.w;
        s2 += v.x*v.x + v.y*v.y + v.z*v.z + v.w*v.w;
    }
    #pragma unroll
    for (int off = 32; off >= 1; off >>= 1){
        s  += __shfl_xor(s,  off, 64);
        s2 += __shfl_xor(s2, off, 64);
    }
    if (l == 0){
        float mu = s * (1.0f / HDIM);
        float var = s2 * (1.0f / HDIM) - mu * mu;
        var = fmaxf(var, 0.f);
        mu_g[tok] = mu;
        rs_g[tok] = 1.0f / sqrtf(var + 1e-5f);
    }
}

// ---------------- kernel 2: transpose + fp32->bf16 (weights, per expert) ----------------
__global__ __launch_bounds__(256) void k_transpose_bf(const float* __restrict__ in,
        unsigned short* __restrict__ out, int R, int C){
    __shared__ float tile[32][33];
    size_t mat = (size_t)blockIdx.z * R * C;
    int bx = blockIdx.x * 32;   // col base
    int by = blockIdx.y * 32;   // row base
    int x = threadIdx.x, y = threadIdx.y;
    const float* ip = in + mat;
    unsigned short* op = out + mat;
    #pragma unroll
    for (int i = 0; i < 32; i += 8)
        tile[y + i][x] = ip[(size_t)(by + y + i) * C + (bx + x)];
    __syncthreads();
    #pragma unroll
    for (int i = 0; i < 32; i += 8)
        op[(size_t)(bx + y + i) * R + (by + x)] = f2bf(tile[x][y + i]);
}

// ---------------- kernel 3: fused fp32 routing (unchanged, verified) ----------------
__global__ __launch_bounds__(256) void k_route(
    const float* __restrict__ h, const float* __restrict__ tok_emb,
    const float* __restrict__ ln_g, const float* __restrict__ ln_b,
    const float* __restrict__ Wg, const float* __restrict__ bg,
    const float* __restrict__ Wf, const float* __restrict__ bfv,
    const float* __restrict__ Wr, const float* __restrict__ br,
    const float* __restrict__ mu_g, const float* __restrict__ rs_g,
    float* __restrict__ tprob, int* __restrict__ list, int* __restrict__ cnt,
    float* __restrict__ imp_part)
{
    __shared__ __align__(16) char smem[62208];
    float* lgs  = (float*)(smem);                      // [1024]
    float* lbs  = (float*)(smem + 4096);               // [1024]
    float (*hsT)[64]  = (float(*)[64])(smem + 8192);   // [64 k][64 tok]
    float (*wgs)[32]  = (float(*)[32])(smem + 24576);  // [64 k][32 c]
    float (*gacc)[32] = (float(*)[32])(smem + 32768);  // [64 tok][32 c]
    float* mus = (float*)(smem + 40960);               // [64]
    float* rss = (float*)(smem + 41216);               // [64]
    float (*wrs)[4]     = (float(*)[4])(smem + 41472); // [64][4]
    float (*logit_s)[5] = (float(*)[5])(smem + 42496);
    float (*prob_s)[5]  = (float(*)[5])(smem + 43776);
    int* lcnt  = (int*)(smem + 45056);
    int* lbase = (int*)(smem + 45072);
    float (*agT)[64] = (float(*)[64])(smem);           // [64 j][64 tok]
    float (*wfs)[64] = (float(*)[64])(smem + 16384);   // [64 k][64 f]
    float (*uT)[64]  = (float(*)[64])(smem + 45824);   // [64 f][64 tok]

    int tid = threadIdx.x;
    int t0 = blockIdx.x * 64;

    ((float4*)lgs)[tid] = ((const float4*)ln_g)[tid];
    ((float4*)lbs)[tid] = ((const float4*)ln_b)[tid];
    if (tid < 64){ mus[tid] = mu_g[t0 + tid]; rss[tid] = rs_g[t0 + tid]; }
    if (tid < 64) ((float4*)wrs)[tid] = ((const float4*)Wr)[tid];
    if (tid < 4) lcnt[tid] = 0;
    __syncthreads();

    int l = tid & 63, w = tid >> 6;
    int tg = l & 7, cg = l >> 3, q = w;
    float g_[8][4];
    #pragma unroll
    for (int i=0;i<8;++i){ g_[i][0]=0.f; g_[i][1]=0.f; g_[i][2]=0.f; g_[i][3]=0.f; }
    int tokrow = tid >> 2;
    float m_ = mus[tokrow], r_ = rss[tokrow];
    const float* hrow = h + (size_t)(t0 + tokrow) * HDIM;

    for (int k0 = 0; k0 < HDIM; k0 += 64){
        #pragma unroll
        for (int p = 0; p < 4; ++p){
            int f4 = (tid & 3) + 4 * p;
            float4 v = ((const float4*)(hrow + k0))[f4];
            int c = f4 * 4;
            hsT[c+0][tokrow] = (v.x - m_) * r_ * lgs[k0+c+0] + lbs[k0+c+0];
            hsT[c+1][tokrow] = (v.y - m_) * r_ * lgs[k0+c+1] + lbs[k0+c+1];
            hsT[c+2][tokrow] = (v.z - m_) * r_ * lgs[k0+c+2] + lbs[k0+c+2];
            hsT[c+3][tokrow] = (v.w - m_) * r_ * lgs[k0+c+3] + lbs[k0+c+3];
        }
        {
            int wgrow = tid >> 2;
            #pragma unroll
            for (int p = 0; p < 2; ++p){
                int f4 = (tid & 3) + 4 * p;
                ((float4*)wgs[wgrow])[f4] = ((const float4*)(Wg + (size_t)(k0 + wgrow) * DGZ))[f4];
            }
        }
        __syncthreads();
        #pragma unroll
        for (int kk16 = 0; kk16 < 16; ++kk16){
            int kk = q * 16 + kk16;
            float4 a0 = ((float4*)hsT[kk])[tg*2];
            float4 a1 = ((float4*)hsT[kk])[tg*2+1];
            float4 wv = ((float4*)wgs[kk])[cg];
            float av[8] = {a0.x,a0.y,a0.z,a0.w,a1.x,a1.y,a1.z,a1.w};
            float wj[4] = {wv.x,wv.y,wv.z,wv.w};
            #pragma unroll
            for (int i=0;i<8;++i){
                g_[i][0] += av[i]*wj[0]; g_[i][1] += av[i]*wj[1];
                g_[i][2] += av[i]*wj[2]; g_[i][3] += av[i]*wj[3];
            }
        }
        __syncthreads();
    }
    for (int qq = 0; qq < 4; ++qq){
        if (w == qq){
            #pragma unroll
            for (int i=0;i<8;++i){
                int tok = tg*8+i;
                #pragma unroll
                for (int j=0;j<4;++j){
                    int c = cg*4+j;
                    if (qq == 0) gacc[tok][c] = g_[i][j];
                    else gacc[tok][c] += g_[i][j];
                }
            }
        }
        __syncthreads();
    }
    {
        int tokr = tid >> 2;
        #pragma unroll
        for (int p = 0; p < 2; ++p){
            int f4 = (tid & 3) + 4*p;
            float4 v = ((const float4*)(tok_emb + (size_t)(t0 + tokr) * DSZ))[f4];
            int j = f4 * 4;
            agT[j+0][tokr] = v.x; agT[j+1][tokr] = v.y;
            agT[j+2][tokr] = v.z; agT[j+3][tokr] = v.w;
        }
        int c = tid & 31, tok8 = (tid >> 5) * 8;
        float bgc = bg[c];
        #pragma unroll
        for (int i=0;i<8;++i){
            int tok = tok8 + i;
            agT[32 + c][tok] = gelu_f(gacc[tok][c] + bgc);
        }
        int row = tid >> 2;
        #pragma unroll
        for (int p = 0; p < 4; ++p){
            int f4 = (tid & 3) + 4*p;
            ((float4*)wfs[row])[f4] = ((const float4*)(Wf + (size_t)row * FMZ))[f4];
        }
    }
    __syncthreads();
    {
        int tok = tid & 63, fq = tid >> 6;
        float u_[16];
        #pragma unroll
        for (int i=0;i<16;++i) u_[i]=0.f;
        for (int j = 0; j < 64; ++j){
            float a = agT[j][tok];
            float wv[16];
            *(float4*)&wv[0]  = ((float4*)wfs[j])[fq*4+0];
            *(float4*)&wv[4]  = ((float4*)wfs[j])[fq*4+1];
            *(float4*)&wv[8]  = ((float4*)wfs[j])[fq*4+2];
            *(float4*)&wv[12] = ((float4*)wfs[j])[fq*4+3];
            #pragma unroll
            for (int i=0;i<16;++i) u_[i] += a * wv[i];
        }
        #pragma unroll
        for (int i=0;i<16;++i){
            int f = fq*16+i;
            uT[f][tok] = gelu_f(u_[i] + bfv[f]);
        }
    }
    __syncthreads();
    {
        int tok = tid & 63, e = tid >> 6;
        float lt = 0.f;
        #pragma unroll 8
        for (int f = 0; f < 64; ++f) lt += uT[f][tok] * wrs[f][e];
        logit_s[tok][e] = lt + br[e];
    }
    __syncthreads();
    int my_e = 0, my_pos = 0;
    if (tid < 64){
        int tok = tid;
        float l0 = logit_s[tok][0], l1 = logit_s[tok][1];
        float l2 = logit_s[tok][2], l3 = logit_s[tok][3];
        float mx = fmaxf(fmaxf(l0,l1), fmaxf(l2,l3));
        float p0 = expf(l0-mx), p1 = expf(l1-mx), p2 = expf(l2-mx), p3 = expf(l3-mx);
        float inv = 1.0f / (p0+p1+p2+p3);
        int be = 0; float bp = p0;
        if (p1 > bp){ bp = p1; be = 1; }
        if (p2 > bp){ bp = p2; be = 2; }
        if (p3 > bp){ bp = p3; be = 3; }
        tprob[t0 + tok] = bp * inv;
        prob_s[tok][0] = p0*inv; prob_s[tok][1] = p1*inv;
        prob_s[tok][2] = p2*inv; prob_s[tok][3] = p3*inv;
        my_e = be;
        my_pos = atomicAdd(&lcnt[be], 1);
    }
    __syncthreads();
    if (tid < 4) lbase[tid] = atomicAdd(&cnt[tid], lcnt[tid]);
    __syncthreads();
    if (tid < 64) list[my_e * NTOK + lbase[my_e] + my_pos] = t0 + tid;
    if (tid < 4){
        float s = 0.f;
        for (int t = 0; t < 64; ++t) s += prob_s[t][tid];
        imp_part[blockIdx.x * 4 + tid] = s;
    }
}

// ---------------- kernel 3b: pack h rows into routing order (fp32 -> bf16) ----------------
__global__ __launch_bounds__(256) void k_pack(const float* __restrict__ h,
        const int* __restrict__ list, const int* __restrict__ cnt,
        unsigned short* __restrict__ Ap){
    int wv = threadIdx.x >> 6, l = threadIdx.x & 63;
    int p = blockIdx.x * 4 + wv;
    int b1 = cnt[0], b2 = b1 + cnt[1], b3 = b2 + cnt[2];
    int e, g;
    if (p < b1){ e = 0; g = p; }
    else if (p < b2){ e = 1; g = p - b1; }
    else if (p < b3){ e = 2; g = p - b2; }
    else { e = 3; g = p - b3; }
    int tok = list[e * NTOK + g];
    const float4* src = (const float4*)(h + (size_t)tok * HDIM);
    ushort4* dst = (ushort4*)(Ap + (size_t)p * HDIM);
    #pragma unroll
    for (int i = 0; i < 4; ++i){
        float4 v = src[l + 64 * i];
        ushort4 o; o.x = f2bf(v.x); o.y = f2bf(v.y); o.z = f2bf(v.z); o.w = f2bf(v.w);
        dst[l + 64 * i] = o;
    }
}

// ---------------- grouped GEMM v10: r11 core + DOUBLE-BUFFER minimum-2-phase (T3) ----------------
// 256 thr = 4 waves (2M x 2N), 128x128 tile, BK=64, LDS 64 KiB = 2 buffers x (A 16KB + B 16KB).
// Per K-step (ONE barrier): STAGE(t+1 -> other buf) issued FIRST, then ds_read+MFMA on cur buf
// (loads fly during compute), then __syncthreads() (compiler drains vmcnt/lgkm once, m97 style).
// 2-step unrolled body keeps buffer offsets compile-time (no runtime cur VALU).
// Overwrite-safe: buf^1 was last read in step t-1, all waves passed t-1's barrier before t stages.
// Swizzle (verified 0-conflict r2/r4/r11): LDS[row][cp] = G[row][cp ^ (row&7)], source pre-swizzled,
// read XORs byte with (l&7)<<4. Flat live-tile dispatch + m204 bijective XCD swizzle (r10/r11).
template<int KTD, int NT, bool PH1, int NWG>
__global__ __launch_bounds__(256) void k_gemm(
    const unsigned short* __restrict__ Abase,
    const unsigned short* __restrict__ Bbase,
    const int* __restrict__ list, const int* __restrict__ cnt_g,
    const float* __restrict__ bias,
    unsigned short* __restrict__ A1out,
    const float* __restrict__ hres,
    const float* __restrict__ tprob,
    float* __restrict__ outp)
{
    constexpr int NKT = KTD / 64;
    __shared__ __align__(16) unsigned short As[2 * 128 * 64];
    __shared__ __align__(16) unsigned short Bs[2 * 128 * 64];
    constexpr int GX = NT / 128;               // 16 (PH1) or 8 (PH2)

    // m204 bijective XCD swizzle over the flat 1-D grid
    int p = blockIdx.x;
    int xcd = p & 7, pos = p >> 3;
    constexpr int Q = NWG >> 3, R = NWG & 7;
    int base = xcd < R ? xcd * (Q + 1) : R * (Q + 1) + (xcd - R) * Q;
    int fl = base + pos;
    int mt = fl / GX, nn = fl % GX;

    // active-tile prefix mapping: mt -> (expert e, packed base pb, local m-tile)
    int c0 = cnt_g[0], c1 = cnt_g[1], c2 = cnt_g[2], c3 = cnt_g[3];
    int nt0 = (c0 + 127) >> 7, nt1 = (c1 + 127) >> 7, nt2 = (c2 + 127) >> 7;
    int nt3 = (c3 + 127) >> 7;
    if (mt >= nt0 + nt1 + nt2 + nt3) return;
    int e = 0, pb = 0, mtl = mt, cnt = c0;
    if (mtl >= nt0){ mtl -= nt0; pb += c0; e = 1; cnt = c1;
        if (mtl >= nt1){ mtl -= nt1; pb += c1; e = 2; cnt = c2;
            if (mtl >= nt2){ mtl -= nt2; pb += c2; e = 3; cnt = c3; } } }
    int m0 = mtl * 128;
    int n0 = nn * 128;

    int tid = threadIdx.x, w = tid >> 6, l = tid & 63;
    int wr = w >> 1, wc = w & 1;

    // staging: instr i covers rows 8w+(l>>3)+32i; source chunk pre-swizzled
    int csw = ((l & 7) ^ (l >> 3)) * 8;
    const unsigned short* aptr[4];
    const unsigned short* bptr[4];
    #pragma unroll
    for (int i = 0; i < 4; ++i){
        int row = 8 * w + (l >> 3) + 32 * i;
        int ga = m0 + row; if (ga > cnt - 1) ga = cnt - 1;
        aptr[i] = Abase + (size_t)(pb + ga) * KTD + csw;
        bptr[i] = Bbase + ((size_t)e * NT + (n0 + row)) * KTD + csw;
    }
    f32x4 acc[4][4] = {};
    int rsw = (l & 7) << 4;

#define STAGE8(K0, DOF) do { \
    gld_lds16(aptr[0] + (K0), (char*)As + (DOF) + w * 1024 + 0 * 4096); \
    gld_lds16(aptr[1] + (K0), (char*)As + (DOF) + w * 1024 + 1 * 4096); \
    gld_lds16(aptr[2] + (K0), (char*)As + (DOF) + w * 1024 + 2 * 4096); \
    gld_lds16(aptr[3] + (K0), (char*)As + (DOF) + w * 1024 + 3 * 4096); \
    gld_lds16(bptr[0] + (K0), (char*)Bs + (DOF) + w * 1024 + 0 * 4096); \
    gld_lds16(bptr[1] + (K0), (char*)Bs + (DOF) + w * 1024 + 1 * 4096); \
    gld_lds16(bptr[2] + (K0), (char*)Bs + (DOF) + w * 1024 + 2 * 4096); \
    gld_lds16(bptr[3] + (K0), (char*)Bs + (DOF) + w * 1024 + 3 * 4096); } while(0)
#define KSTEP(T, CUR, NXT) do { \
    if ((T) + 1 < NKT) STAGE8(((T) + 1) * 64, NXT); \
    _Pragma("unroll") \
    for (int kk = 0; kk < 2; ++kk){ \
        bf16x8 a[4], b[4]; \
        _Pragma("unroll") \
        for (int m = 0; m < 4; ++m) \
            a[m] = *(const bf16x8*)((const char*)As + (CUR) + (wr*64 + m*16 + (l&15))*128 + ((kk*64 + (l>>4)*16) ^ rsw)); \
        _Pragma("unroll") \
        for (int n = 0; n < 4; ++n) \
            b[n] = *(const bf16x8*)((const char*)Bs + (CUR) + (wc*64 + n*16 + (l&15))*128 + ((kk*64 + (l>>4)*16) ^ rsw)); \
        _Pragma("unroll") \
        for (int m = 0; m < 4; ++m) \
            _Pragma("unroll") \
            for (int n = 0; n < 4; ++n) \
                acc[m][n] = __builtin_amdgcn_mfma_f32_16x16x32_bf16(a[m], b[n], acc[m][n], 0, 0, 0); \
    } \
    __syncthreads(); } while(0)

    // prologue: stage tile 0 into buf0; drain; barrier (compiler emits the waitcnts)
    STAGE8(0, 0);
    __syncthreads();

    #pragma unroll 1
    for (int kt = 0; kt < NKT; kt += 2){
        KSTEP(kt,     0,     16384);   // compute buf0, stage t+1 -> buf1
        KSTEP(kt + 1, 16384, 0);       // compute buf1, stage t+2 -> buf0
    }
#undef STAGE8
#undef KSTEP

    // epilogue: C/D layout col = lane&15 (+16*n), row = (lane>>4)*4 + reg (+16*m)
    float bs[4];
    #pragma unroll
    for (int n = 0; n < 4; ++n)
        bs[n] = bias[e * NT + n0 + wc * 64 + n * 16 + (l & 15)];
    #pragma unroll
    for (int m = 0; m < 4; ++m){
        #pragma unroll
        for (int r = 0; r < 4; ++r){
            int row = wr * 64 + m * 16 + (l >> 4) * 4 + r;
            int gg = m0 + row;
            if (gg < cnt){
                if (PH1){
                    #pragma unroll
                    for (int n = 0; n < 4; ++n){
                        int col = n0 + wc * 64 + n * 16 + (l & 15);
                        float v = acc[m][n][r] + bs[n];
                        A1out[(size_t)(pb + gg) * FFZ + col] = f2bf(gelu_f(v));
                    }
                } else {
                    int tok = list[e * NTOK + gg];
                    float sc = 0.5f * tprob[tok];
                    #pragma unroll
                    for (int n = 0; n < 4; ++n){
                        int col = n0 + wc * 64 + n * 16 + (l & 15);
                        float v = acc[m][n][r] + bs[n];
                        size_t o = (size_t)tok * HDIM + col;
                        outp[o] = hres[o] + sc * v;
                    }
                }
            }
        }
    }
}

// ---------------- final: lb_loss ----------------
__global__ void k_final(const float* __restrict__ imp_part, const int* __restrict__ cnt,
                        float* __restrict__ outp){
    __shared__ float imp_s[4];
    int tid = threadIdx.x;
    if (tid < 4){
        float s = 0.f;
        for (int b = 0; b < 256; ++b) s += imp_part[b*4 + tid];
        imp_s[tid] = s;
    }
    __syncthreads();
    if (tid == 0){
        float lb = 0.f;
        #pragma unroll
        for (int e = 0; e < 4; ++e) lb += imp_s[e] * (float)cnt[e];
        outp[(size_t)NTOK * HDIM] = (float)NEXP * lb / ((float)NTOK * (float)NTOK + 1e-8f);
    }
}

extern "C" void kernel_launch(void* const* d_in, const int* in_sizes, int n_in,
                              void* d_out, int out_size, void* d_ws, size_t ws_size,
                              hipStream_t stream){
    const float* h       = (const float*)d_in[0];
    const float* tok_emb = (const float*)d_in[1];
    const float* ln_g = (const float*)d_in[3];
    const float* ln_b = (const float*)d_in[4];
    const float* Wg   = (const float*)d_in[5];
    const float* bg   = (const float*)d_in[6];
    const float* Wf   = (const float*)d_in[7];
    const float* bfv  = (const float*)d_in[8];
    const float* Wr   = (const float*)d_in[9];
    const float* br   = (const float*)d_in[10];
    const float* W1   = (const float*)d_in[11];
    const float* b1   = (const float*)d_in[12];
    const float* W2   = (const float*)d_in[13];
    const float* b2   = (const float*)d_in[14];
    float* outp = (float*)d_out;
    char* ws = (char*)d_ws;

    unsigned short* Ap   = (unsigned short*)(ws);               // 33554432 B  packed h rows (bf16)
    unsigned short* W1T  = (unsigned short*)(ws + 33554432);    // 16777216 B  [E][FFZ][HDIM]
    unsigned short* W2T  = (unsigned short*)(ws + 50331648);    // 16777216 B  [E][HDIM][FFZ]
    unsigned short* A1   = (unsigned short*)(ws + 67108864);    // 67108864 B  packed [NTOK][FFZ]
    float* mu_g  = (float*)(ws + 134217728);
    float* rs_g  = (float*)(ws + 134283264);
    float* tprob = (float*)(ws + 134348800);
    int*   list  = (int*)(ws + 134414336);                      // [E][NTOK]
    int*   cnt   = (int*)(ws + 134676480);                      // [E]
    float* imp   = (float*)(ws + 134676736);                    // [256][E]

    // flat 1-D grids over active 128x128 tiles
    constexpr int NWG1 = (NTOK/128 + 3) * (FFZ/128);   // 2096
    constexpr int NWG2 = (NTOK/128 + 3) * (HDIM/128);  // 1048

    hipMemsetAsync(cnt, 0, NEXP * sizeof(int), stream);
    k_stats<<<NTOK/4, 256, 0, stream>>>(h, mu_g, rs_g);
    k_transpose_bf<<<dim3(FFZ/32, HDIM/32, NEXP), dim3(32,8), 0, stream>>>(W1, W1T, HDIM, FFZ);
    k_transpose_bf<<<dim3(HDIM/32, FFZ/32, NEXP), dim3(32,8), 0, stream>>>(W2, W2T, FFZ, HDIM);
    k_route<<<NTOK/64, 256, 0, stream>>>(h, tok_emb, ln_g, ln_b, Wg, bg, Wf, bfv, Wr, br,
                                         mu_g, rs_g, tprob, list, cnt, imp);
    k_pack<<<NTOK/4, 256, 0, stream>>>(h, list, cnt, Ap);
    k_gemm<HDIM, FFZ, true, NWG1><<<NWG1, 256, 0, stream>>>(
        Ap, W1T, list, cnt, b1, A1, nullptr, nullptr, nullptr);
    k_gemm<FFZ, HDIM, false, NWG2><<<NWG2, 256, 0, stream>>>(
        A1, W2T, list, cnt, b2, nullptr, h, tprob, outp);
    k_final<<<1, 64, 0, stream>>>(imp, cnt, outp);
}

// Round 13
// 361.434 us; speedup vs baseline: 1.0773x; 1.0773x over previous
//
#include <hip/hip_runtime.h>
#include <hip/hip_bf16.h>
#include <math.h>

#define NTOK 16384
#define HDIM 1024
#define DSZ 32
#define DGZ 32
#define FMZ 64
#define NEXP 4
#define FFZ 2048

typedef __attribute__((ext_vector_type(4))) float f32x4;
typedef __attribute__((ext_vector_type(8))) short bf16x8;

__device__ __forceinline__ unsigned short f2bf(float f){
    union { float f; unsigned int u; } v; v.f = f;
    unsigned int r = (v.u + 0x7FFFu + ((v.u >> 16) & 1u)) >> 16;
    return (unsigned short)r;
}
__device__ __forceinline__ float gelu_f(float x){
    return 0.5f * x * (1.0f + erff(x * 0.70710678118654752440f));
}
__device__ __forceinline__ void gld_lds16(const void* g, void* s){
    __builtin_amdgcn_global_load_lds((const __attribute__((address_space(1))) unsigned int*)g,
                                     (__attribute__((address_space(3))) unsigned int*)s, 16, 0, 0);
}

// ---------------- kernel 1: both weight transposes in one launch ----------------
// grid (64, 32, 8): z<4 -> W1 expert z (R=HDIM,C=FFZ); z>=4 -> W2 expert z-4 (R=FFZ,C=HDIM, bx/by swapped)
__global__ __launch_bounds__(256) void k_transpose2(const float* __restrict__ W1,
        const float* __restrict__ W2, unsigned short* __restrict__ W1T,
        unsigned short* __restrict__ W2T){
    __shared__ float tile[32][33];
    int z = blockIdx.z;
    const float* in; unsigned short* out; int R, C, bx, by;
    if (z < 4){
        in = W1 + (size_t)z * HDIM * FFZ; out = W1T + (size_t)z * HDIM * FFZ;
        R = HDIM; C = FFZ; bx = blockIdx.x * 32; by = blockIdx.y * 32;
    } else {
        int e = z - 4;
        in = W2 + (size_t)e * FFZ * HDIM; out = W2T + (size_t)e * FFZ * HDIM;
        R = FFZ; C = HDIM; bx = blockIdx.y * 32; by = blockIdx.x * 32;
    }
    int x = threadIdx.x, y = threadIdx.y;
    #pragma unroll
    for (int i = 0; i < 32; i += 8)
        tile[y + i][x] = in[(size_t)(by + y + i) * C + (bx + x)];
    __syncthreads();
    #pragma unroll
    for (int i = 0; i < 32; i += 8)
        out[(size_t)(bx + y + i) * R + (by + x)] = f2bf(tile[x][y + i]);
}

// ---------------- kernel 2: fused routing (stats fused in; verified core unchanged) ----------------
__global__ __launch_bounds__(256) void k_route(
    const float* __restrict__ h, const float* __restrict__ tok_emb,
    const float* __restrict__ ln_g, const float* __restrict__ ln_b,
    const float* __restrict__ Wg, const float* __restrict__ bg,
    const float* __restrict__ Wf, const float* __restrict__ bfv,
    const float* __restrict__ Wr, const float* __restrict__ br,
    float* __restrict__ tprob, int* __restrict__ list, int* __restrict__ cnt,
    float* __restrict__ imp_part)
{
    __shared__ __align__(16) char smem[62208];
    float* lgs  = (float*)(smem);
    float* lbs  = (float*)(smem + 4096);
    float (*hsT)[64]  = (float(*)[64])(smem + 8192);
    float (*wgs)[32]  = (float(*)[32])(smem + 24576);
    float (*gacc)[32] = (float(*)[32])(smem + 32768);
    float* mus = (float*)(smem + 40960);
    float* rss = (float*)(smem + 41216);
    float (*wrs)[4]     = (float(*)[4])(smem + 41472);
    float (*logit_s)[5] = (float(*)[5])(smem + 42496);
    float (*prob_s)[5]  = (float(*)[5])(smem + 43776);
    int* lcnt  = (int*)(smem + 45056);
    int* lbase = (int*)(smem + 45072);
    float (*agT)[64] = (float(*)[64])(smem);
    float (*wfs)[64] = (float(*)[64])(smem + 16384);
    float (*uT)[64]  = (float(*)[64])(smem + 45824);

    int tid = threadIdx.x;
    int t0 = blockIdx.x * 64;

    ((float4*)lgs)[tid] = ((const float4*)ln_g)[tid];
    ((float4*)lbs)[tid] = ((const float4*)ln_b)[tid];
    if (tid < 64) ((float4*)wrs)[tid] = ((const float4*)Wr)[tid];
    if (tid < 4) lcnt[tid] = 0;

    // ---- fused stats pre-pass: 4 lanes per token row ----
    {
        int tokrow = tid >> 2, q4 = tid & 3;
        const float4* hp = (const float4*)(h + (size_t)(t0 + tokrow) * HDIM);
        float s = 0.f, s2 = 0.f;
        #pragma unroll 8
        for (int i = 0; i < 64; ++i){
            float4 v = hp[q4 + 4 * i];
            s  += v.x + v.y + v.z + v.w;
            s2 += v.x*v.x + v.y*v.y + v.z*v.z + v.w*v.w;
        }
        s  += __shfl_xor(s, 1, 64);  s2 += __shfl_xor(s2, 1, 64);
        s  += __shfl_xor(s, 2, 64);  s2 += __shfl_xor(s2, 2, 64);
        if (q4 == 0){
            float mu = s * (1.0f / HDIM);
            float var = fmaxf(s2 * (1.0f / HDIM) - mu * mu, 0.f);
            mus[tokrow] = mu;
            rss[tokrow] = 1.0f / sqrtf(var + 1e-5f);
        }
    }
    __syncthreads();

    int l = tid & 63, w = tid >> 6;
    int tg = l & 7, cg = l >> 3, q = w;
    float g_[8][4];
    #pragma unroll
    for (int i=0;i<8;++i){ g_[i][0]=0.f; g_[i][1]=0.f; g_[i][2]=0.f; g_[i][3]=0.f; }
    int tokrow = tid >> 2;
    float m_ = mus[tokrow], r_ = rss[tokrow];
    const float* hrow = h + (size_t)(t0 + tokrow) * HDIM;

    for (int k0 = 0; k0 < HDIM; k0 += 64){
        #pragma unroll
        for (int p = 0; p < 4; ++p){
            int f4 = (tid & 3) + 4 * p;
            float4 v = ((const float4*)(hrow + k0))[f4];
            int c = f4 * 4;
            hsT[c+0][tokrow] = (v.x - m_) * r_ * lgs[k0+c+0] + lbs[k0+c+0];
            hsT[c+1][tokrow] = (v.y - m_) * r_ * lgs[k0+c+1] + lbs[k0+c+1];
            hsT[c+2][tokrow] = (v.z - m_) * r_ * lgs[k0+c+2] + lbs[k0+c+2];
            hsT[c+3][tokrow] = (v.w - m_) * r_ * lgs[k0+c+3] + lbs[k0+c+3];
        }
        {
            int wgrow = tid >> 2;
            #pragma unroll
            for (int p = 0; p < 2; ++p){
                int f4 = (tid & 3) + 4 * p;
                ((float4*)wgs[wgrow])[f4] = ((const float4*)(Wg + (size_t)(k0 + wgrow) * DGZ))[f4];
            }
        }
        __syncthreads();
        #pragma unroll
        for (int kk16 = 0; kk16 < 16; ++kk16){
            int kk = q * 16 + kk16;
            float4 a0 = ((float4*)hsT[kk])[tg*2];
            float4 a1 = ((float4*)hsT[kk])[tg*2+1];
            float4 wv = ((float4*)wgs[kk])[cg];
            float av[8] = {a0.x,a0.y,a0.z,a0.w,a1.x,a1.y,a1.z,a1.w};
            float wj[4] = {wv.x,wv.y,wv.z,wv.w};
            #pragma unroll
            for (int i=0;i<8;++i){
                g_[i][0] += av[i]*wj[0]; g_[i][1] += av[i]*wj[1];
                g_[i][2] += av[i]*wj[2]; g_[i][3] += av[i]*wj[3];
            }
        }
        __syncthreads();
    }
    for (int qq = 0; qq < 4; ++qq){
        if (w == qq){
            #pragma unroll
            for (int i=0;i<8;++i){
                int tok = tg*8+i;
                #pragma unroll
                for (int j=0;j<4;++j){
                    int c = cg*4+j;
                    if (qq == 0) gacc[tok][c] = g_[i][j];
                    else gacc[tok][c] += g_[i][j];
                }
            }
        }
        __syncthreads();
    }
    {
        int tokr = tid >> 2;
        #pragma unroll
        for (int p = 0; p < 2; ++p){
            int f4 = (tid & 3) + 4*p;
            float4 v = ((const float4*)(tok_emb + (size_t)(t0 + tokr) * DSZ))[f4];
            int j = f4 * 4;
            agT[j+0][tokr] = v.x; agT[j+1][tokr] = v.y;
            agT[j+2][tokr] = v.z; agT[j+3][tokr] = v.w;
        }
        int c = tid & 31, tok8 = (tid >> 5) * 8;
        float bgc = bg[c];
        #pragma unroll
        for (int i=0;i<8;++i){
            int tok = tok8 + i;
            agT[32 + c][tok] = gelu_f(gacc[tok][c] + bgc);
        }
        int row = tid >> 2;
        #pragma unroll
        for (int p = 0; p < 4; ++p){
            int f4 = (tid & 3) + 4*p;
            ((float4*)wfs[row])[f4] = ((const float4*)(Wf + (size_t)row * FMZ))[f4];
        }
    }
    __syncthreads();
    {
        int tok = tid & 63, fq = tid >> 6;
        float u_[16];
        #pragma unroll
        for (int i=0;i<16;++i) u_[i]=0.f;
        for (int j = 0; j < 64; ++j){
            float a = agT[j][tok];
            float wv[16];
            *(float4*)&wv[0]  = ((float4*)wfs[j])[fq*4+0];
            *(float4*)&wv[4]  = ((float4*)wfs[j])[fq*4+1];
            *(float4*)&wv[8]  = ((float4*)wfs[j])[fq*4+2];
            *(float4*)&wv[12] = ((float4*)wfs[j])[fq*4+3];
            #pragma unroll
            for (int i=0;i<16;++i) u_[i] += a * wv[i];
        }
        #pragma unroll
        for (int i=0;i<16;++i){
            int f = fq*16+i;
            uT[f][tok] = gelu_f(u_[i] + bfv[f]);
        }
    }
    __syncthreads();
    {
        int tok = tid & 63, e = tid >> 6;
        float lt = 0.f;
        #pragma unroll 8
        for (int f = 0; f < 64; ++f) lt += uT[f][tok] * wrs[f][e];
        logit_s[tok][e] = lt + br[e];
    }
    __syncthreads();
    int my_e = 0, my_pos = 0;
    if (tid < 64){
        int tok = tid;
        float l0 = logit_s[tok][0], l1 = logit_s[tok][1];
        float l2 = logit_s[tok][2], l3 = logit_s[tok][3];
        float mx = fmaxf(fmaxf(l0,l1), fmaxf(l2,l3));
        float p0 = expf(l0-mx), p1 = expf(l1-mx), p2 = expf(l2-mx), p3 = expf(l3-mx);
        float inv = 1.0f / (p0+p1+p2+p3);
        int be = 0; float bp = p0;
        if (p1 > bp){ bp = p1; be = 1; }
        if (p2 > bp){ bp = p2; be = 2; }
        if (p3 > bp){ bp = p3; be = 3; }
        tprob[t0 + tok] = bp * inv;
        prob_s[tok][0] = p0*inv; prob_s[tok][1] = p1*inv;
        prob_s[tok][2] = p2*inv; prob_s[tok][3] = p3*inv;
        my_e = be;
        my_pos = atomicAdd(&lcnt[be], 1);
    }
    __syncthreads();
    if (tid < 4) lbase[tid] = atomicAdd(&cnt[tid], lcnt[tid]);
    __syncthreads();
    if (tid < 64) list[my_e * NTOK + lbase[my_e] + my_pos] = t0 + tid;
    if (tid < 4){
        float s = 0.f;
        for (int t = 0; t < 64; ++t) s += prob_s[t][tid];
        imp_part[blockIdx.x * 4 + tid] = s;
    }
}

// ---------------- kernel 3: pack h rows into routing order (fp32 -> bf16) ----------------
__global__ __launch_bounds__(256) void k_pack(const float* __restrict__ h,
        const int* __restrict__ list, const int* __restrict__ cnt,
        unsigned short* __restrict__ Ap){
    int wv = threadIdx.x >> 6, l = threadIdx.x & 63;
    int p = blockIdx.x * 4 + wv;
    int b1 = cnt[0], b2 = b1 + cnt[1], b3 = b2 + cnt[2];
    int e, g;
    if (p < b1){ e = 0; g = p; }
    else if (p < b2){ e = 1; g = p - b1; }
    else if (p < b3){ e = 2; g = p - b2; }
    else { e = 3; g = p - b3; }
    int tok = list[e * NTOK + g];
    const float4* src = (const float4*)(h + (size_t)tok * HDIM);
    ushort4* dst = (ushort4*)(Ap + (size_t)p * HDIM);
    #pragma unroll
    for (int i = 0; i < 4; ++i){
        float4 v = src[l + 64 * i];
        ushort4 o; o.x = f2bf(v.x); o.y = f2bf(v.y); o.z = f2bf(v.z); o.w = f2bf(v.w);
        dst[l + 64 * i] = o;
    }
}

// ---------------- grouped GEMM v9 (r11 best, UNCHANGED): 128x128, 32KB LDS, flat dispatch ----------------
template<int KTD, int NT, bool PH1, int NWG>
__global__ __launch_bounds__(256) void k_gemm(
    const unsigned short* __restrict__ Abase,
    const unsigned short* __restrict__ Bbase,
    const int* __restrict__ list, const int* __restrict__ cnt_g,
    const float* __restrict__ bias,
    unsigned short* __restrict__ A1out,
    const float* __restrict__ hres,
    const float* __restrict__ tprob,
    float* __restrict__ outp)
{
    __shared__ __align__(16) unsigned short As[128 * 64];
    __shared__ __align__(16) unsigned short Bs[128 * 64];
    constexpr int GX = NT / 128;

    int p = blockIdx.x;
    int xcd = p & 7, pos = p >> 3;
    constexpr int Q = NWG >> 3, R = NWG & 7;
    int base = xcd < R ? xcd * (Q + 1) : R * (Q + 1) + (xcd - R) * Q;
    int fl = base + pos;
    int mt = fl / GX, nn = fl % GX;

    int c0 = cnt_g[0], c1 = cnt_g[1], c2 = cnt_g[2], c3 = cnt_g[3];
    int nt0 = (c0 + 127) >> 7, nt1 = (c1 + 127) >> 7, nt2 = (c2 + 127) >> 7;
    int nt3 = (c3 + 127) >> 7;
    if (mt >= nt0 + nt1 + nt2 + nt3) return;
    int e = 0, pb = 0, mtl = mt, cnt = c0;
    if (mtl >= nt0){ mtl -= nt0; pb += c0; e = 1; cnt = c1;
        if (mtl >= nt1){ mtl -= nt1; pb += c1; e = 2; cnt = c2;
            if (mtl >= nt2){ mtl -= nt2; pb += c2; e = 3; cnt = c3; } } }
    int m0 = mtl * 128;
    int n0 = nn * 128;

    int tid = threadIdx.x, w = tid >> 6, l = tid & 63;
    int wr = w >> 1, wc = w & 1;

    int csw = ((l & 7) ^ (l >> 3)) * 8;
    const unsigned short* aptr[4];
    const unsigned short* bptr[4];
    #pragma unroll
    for (int i = 0; i < 4; ++i){
        int row = 8 * w + (l >> 3) + 32 * i;
        int ga = m0 + row; if (ga > cnt - 1) ga = cnt - 1;
        aptr[i] = Abase + (size_t)(pb + ga) * KTD + csw;
        bptr[i] = Bbase + ((size_t)e * NT + (n0 + row)) * KTD + csw;
    }
    f32x4 acc[4][4] = {};
    int rsw = (l & 7) << 4;
    for (int k0 = 0; k0 < KTD; k0 += 64){
        #pragma unroll
        for (int i = 0; i < 4; ++i)
            gld_lds16(aptr[i] + k0, (char*)As + w * 1024 + i * 4096);
        #pragma unroll
        for (int i = 0; i < 4; ++i)
            gld_lds16(bptr[i] + k0, (char*)Bs + w * 1024 + i * 4096);
        __syncthreads();
        #pragma unroll
        for (int kk = 0; kk < 2; ++kk){
            bf16x8 a[4], b[4];
            #pragma unroll
            for (int m = 0; m < 4; ++m)
                a[m] = *(const bf16x8*)((const char*)As + (wr*64 + m*16 + (l&15))*128 + ((kk*64 + (l>>4)*16) ^ rsw));
            #pragma unroll
            for (int n = 0; n < 4; ++n)
                b[n] = *(const bf16x8*)((const char*)Bs + (wc*64 + n*16 + (l&15))*128 + ((kk*64 + (l>>4)*16) ^ rsw));
            #pragma unroll
            for (int m = 0; m < 4; ++m)
                #pragma unroll
                for (int n = 0; n < 4; ++n)
                    acc[m][n] = __builtin_amdgcn_mfma_f32_16x16x32_bf16(a[m], b[n], acc[m][n], 0, 0, 0);
        }
        __syncthreads();
    }

    float bs[4];
    #pragma unroll
    for (int n = 0; n < 4; ++n)
        bs[n] = bias[e * NT + n0 + wc * 64 + n * 16 + (l & 15)];
    #pragma unroll
    for (int m = 0; m < 4; ++m){
        #pragma unroll
        for (int r = 0; r < 4; ++r){
            int row = wr * 64 + m * 16 + (l >> 4) * 4 + r;
            int gg = m0 + row;
            if (gg < cnt){
                if (PH1){
                    #pragma unroll
                    for (int n = 0; n < 4; ++n){
                        int col = n0 + wc * 64 + n * 16 + (l & 15);
                        float v = acc[m][n][r] + bs[n];
                        A1out[(size_t)(pb + gg) * FFZ + col] = f2bf(gelu_f(v));
                    }
                } else {
                    int tok = list[e * NTOK + gg];
                    float sc = 0.5f * tprob[tok];
                    #pragma unroll
                    for (int n = 0; n < 4; ++n){
                        int col = n0 + wc * 64 + n * 16 + (l & 15);
                        float v = acc[m][n][r] + bs[n];
                        size_t o = (size_t)tok * HDIM + col;
                        outp[o] = hres[o] + sc * v;
                    }
                }
            }
        }
    }
}

// ---------------- final: lb_loss ----------------
__global__ void k_final(const float* __restrict__ imp_part, const int* __restrict__ cnt,
                        float* __restrict__ outp){
    __shared__ float imp_s[4];
    int tid = threadIdx.x;
    if (tid < 4){
        float s = 0.f;
        for (int b = 0; b < 256; ++b) s += imp_part[b*4 + tid];
        imp_s[tid] = s;
    }
    __syncthreads();
    if (tid == 0){
        float lb = 0.f;
        #pragma unroll
        for (int e = 0; e < 4; ++e) lb += imp_s[e] * (float)cnt[e];
        outp[(size_t)NTOK * HDIM] = (float)NEXP * lb / ((float)NTOK * (float)NTOK + 1e-8f);
    }
}

extern "C" void kernel_launch(void* const* d_in, const int* in_sizes, int n_in,
                              void* d_out, int out_size, void* d_ws, size_t ws_size,
                              hipStream_t stream){
    const float* h       = (const float*)d_in[0];
    const float* tok_emb = (const float*)d_in[1];
    const float* ln_g = (const float*)d_in[3];
    const float* ln_b = (const float*)d_in[4];
    const float* Wg   = (const float*)d_in[5];
    const float* bg   = (const float*)d_in[6];
    const float* Wf   = (const float*)d_in[7];
    const float* bfv  = (const float*)d_in[8];
    const float* Wr   = (const float*)d_in[9];
    const float* br   = (const float*)d_in[10];
    const float* W1   = (const float*)d_in[11];
    const float* b1   = (const float*)d_in[12];
    const float* W2   = (const float*)d_in[13];
    const float* b2   = (const float*)d_in[14];
    float* outp = (float*)d_out;
    char* ws = (char*)d_ws;

    unsigned short* Ap   = (unsigned short*)(ws);               // 33554432 B  packed h rows (bf16)
    unsigned short* W1T  = (unsigned short*)(ws + 33554432);    // 16777216 B
    unsigned short* W2T  = (unsigned short*)(ws + 50331648);    // 16777216 B
    unsigned short* A1   = (unsigned short*)(ws + 67108864);    // 67108864 B  packed [NTOK][FFZ]
    float* tprob = (float*)(ws + 134348800);
    int*   list  = (int*)(ws + 134414336);                      // [E][NTOK]
    int*   cnt   = (int*)(ws + 134676480);                      // [E]
    float* imp   = (float*)(ws + 134676736);                    // [256][E]

    constexpr int NWG1 = (NTOK/128 + 3) * (FFZ/128);   // 2096
    constexpr int NWG2 = (NTOK/128 + 3) * (HDIM/128);  // 1048

    hipMemsetAsync(cnt, 0, NEXP * sizeof(int), stream);
    k_transpose2<<<dim3(64, 32, 8), dim3(32, 8), 0, stream>>>(W1, W2, W1T, W2T);
    k_route<<<NTOK/64, 256, 0, stream>>>(h, tok_emb, ln_g, ln_b, Wg, bg, Wf, bfv, Wr, br,
                                         tprob, list, cnt, imp);
    k_pack<<<NTOK/4, 256, 0, stream>>>(h, list, cnt, Ap);
    k_gemm<HDIM, FFZ, true, NWG1><<<NWG1, 256, 0, stream>>>(
        Ap, W1T, list, cnt, b1, A1, nullptr, nullptr, nullptr);
    k_gemm<FFZ, HDIM, false, NWG2><<<NWG2, 256, 0, stream>>>(
        A1, W2T, list, cnt, b2, nullptr, h, tprob, outp);
    k_final<<<1, 64, 0, stream>>>(imp, cnt, outp);
}

// Round 14
// 357.178 us; speedup vs baseline: 1.0901x; 1.0119x over previous
//
#include <hip/hip_runtime.h>
#include <hip/hip_bf16.h>
#include <math.h>

#define NTOK 16384
#define HDIM 1024
#define DSZ 32
#define DGZ 32
#define FMZ 64
#define NEXP 4
#define FFZ 2048

typedef __attribute__((ext_vector_type(4))) float f32x4;
typedef __attribute__((ext_vector_type(8))) short bf16x8;

__device__ __forceinline__ unsigned short f2bf(float f){
    union { float f; unsigned int u; } v; v.f = f;
    unsigned int r = (v.u + 0x7FFFu + ((v.u >> 16) & 1u)) >> 16;
    return (unsigned short)r;
}
__device__ __forceinline__ float gelu_f(float x){
    return 0.5f * x * (1.0f + erff(x * 0.70710678118654752440f));
}
__device__ __forceinline__ void gld_lds16(const void* g, void* s){
    __builtin_amdgcn_global_load_lds((const __attribute__((address_space(1))) unsigned int*)g,
                                     (__attribute__((address_space(3))) unsigned int*)s, 16, 0, 0);
}

// ---------------- kernel 1: both weight transposes in one launch (+ cnt zeroing) ----------------
// grid (64, 32, 8): z<4 -> W1 expert z (R=HDIM,C=FFZ); z>=4 -> W2 expert z-4 (R=FFZ,C=HDIM, bx/by swapped)
__global__ __launch_bounds__(256) void k_transpose2(const float* __restrict__ W1,
        const float* __restrict__ W2, unsigned short* __restrict__ W1T,
        unsigned short* __restrict__ W2T, int* __restrict__ cnt){
    __shared__ float tile[32][33];
    if (blockIdx.x == 0 && blockIdx.y == 0 && blockIdx.z == 0 &&
        threadIdx.y == 0 && threadIdx.x < 4)
        cnt[threadIdx.x] = 0;
    int z = blockIdx.z;
    const float* in; unsigned short* out; int R, C, bx, by;
    if (z < 4){
        in = W1 + (size_t)z * HDIM * FFZ; out = W1T + (size_t)z * HDIM * FFZ;
        R = HDIM; C = FFZ; bx = blockIdx.x * 32; by = blockIdx.y * 32;
    } else {
        int e = z - 4;
        in = W2 + (size_t)e * FFZ * HDIM; out = W2T + (size_t)e * FFZ * HDIM;
        R = FFZ; C = HDIM; bx = blockIdx.y * 32; by = blockIdx.x * 32;
    }
    int x = threadIdx.x, y = threadIdx.y;
    #pragma unroll
    for (int i = 0; i < 32; i += 8)
        tile[y + i][x] = in[(size_t)(by + y + i) * C + (bx + x)];
    __syncthreads();
    #pragma unroll
    for (int i = 0; i < 32; i += 8)
        out[(size_t)(bx + y + i) * R + (by + x)] = f2bf(tile[x][y + i]);
}

// ---------------- kernel 2: fused routing (stats + route + h->bf16 conversion tail) ----------------
__global__ __launch_bounds__(256) void k_route(
    const float* __restrict__ h, const float* __restrict__ tok_emb,
    const float* __restrict__ ln_g, const float* __restrict__ ln_b,
    const float* __restrict__ Wg, const float* __restrict__ bg,
    const float* __restrict__ Wf, const float* __restrict__ bfv,
    const float* __restrict__ Wr, const float* __restrict__ br,
    float* __restrict__ tprob, int* __restrict__ list, int* __restrict__ cnt,
    float* __restrict__ imp_part, unsigned short* __restrict__ hbf)
{
    __shared__ __align__(16) char smem[62208];
    float* lgs  = (float*)(smem);
    float* lbs  = (float*)(smem + 4096);
    float (*hsT)[64]  = (float(*)[64])(smem + 8192);
    float (*wgs)[32]  = (float(*)[32])(smem + 24576);
    float (*gacc)[32] = (float(*)[32])(smem + 32768);
    float* mus = (float*)(smem + 40960);
    float* rss = (float*)(smem + 41216);
    float (*wrs)[4]     = (float(*)[4])(smem + 41472);
    float (*logit_s)[5] = (float(*)[5])(smem + 42496);
    float (*prob_s)[5]  = (float(*)[5])(smem + 43776);
    int* lcnt  = (int*)(smem + 45056);
    int* lbase = (int*)(smem + 45072);
    float (*agT)[64] = (float(*)[64])(smem);
    float (*wfs)[64] = (float(*)[64])(smem + 16384);
    float (*uT)[64]  = (float(*)[64])(smem + 45824);

    int tid = threadIdx.x;
    int t0 = blockIdx.x * 64;

    ((float4*)lgs)[tid] = ((const float4*)ln_g)[tid];
    ((float4*)lbs)[tid] = ((const float4*)ln_b)[tid];
    if (tid < 64) ((float4*)wrs)[tid] = ((const float4*)Wr)[tid];
    if (tid < 4) lcnt[tid] = 0;

    // ---- fused stats pre-pass: 4 lanes per token row ----
    {
        int tokrow = tid >> 2, q4 = tid & 3;
        const float4* hp = (const float4*)(h + (size_t)(t0 + tokrow) * HDIM);
        float s = 0.f, s2 = 0.f;
        #pragma unroll 8
        for (int i = 0; i < 64; ++i){
            float4 v = hp[q4 + 4 * i];
            s  += v.x + v.y + v.z + v.w;
            s2 += v.x*v.x + v.y*v.y + v.z*v.z + v.w*v.w;
        }
        s  += __shfl_xor(s, 1, 64);  s2 += __shfl_xor(s2, 1, 64);
        s  += __shfl_xor(s, 2, 64);  s2 += __shfl_xor(s2, 2, 64);
        if (q4 == 0){
            float mu = s * (1.0f / HDIM);
            float var = fmaxf(s2 * (1.0f / HDIM) - mu * mu, 0.f);
            mus[tokrow] = mu;
            rss[tokrow] = 1.0f / sqrtf(var + 1e-5f);
        }
    }
    __syncthreads();

    int l = tid & 63, w = tid >> 6;
    int tg = l & 7, cg = l >> 3, q = w;
    float g_[8][4];
    #pragma unroll
    for (int i=0;i<8;++i){ g_[i][0]=0.f; g_[i][1]=0.f; g_[i][2]=0.f; g_[i][3]=0.f; }
    int tokrow = tid >> 2;
    float m_ = mus[tokrow], r_ = rss[tokrow];
    const float* hrow = h + (size_t)(t0 + tokrow) * HDIM;

    for (int k0 = 0; k0 < HDIM; k0 += 64){
        #pragma unroll
        for (int p = 0; p < 4; ++p){
            int f4 = (tid & 3) + 4 * p;
            float4 v = ((const float4*)(hrow + k0))[f4];
            int c = f4 * 4;
            hsT[c+0][tokrow] = (v.x - m_) * r_ * lgs[k0+c+0] + lbs[k0+c+0];
            hsT[c+1][tokrow] = (v.y - m_) * r_ * lgs[k0+c+1] + lbs[k0+c+1];
            hsT[c+2][tokrow] = (v.z - m_) * r_ * lgs[k0+c+2] + lbs[k0+c+2];
            hsT[c+3][tokrow] = (v.w - m_) * r_ * lgs[k0+c+3] + lbs[k0+c+3];
        }
        {
            int wgrow = tid >> 2;
            #pragma unroll
            for (int p = 0; p < 2; ++p){
                int f4 = (tid & 3) + 4 * p;
                ((float4*)wgs[wgrow])[f4] = ((const float4*)(Wg + (size_t)(k0 + wgrow) * DGZ))[f4];
            }
        }
        __syncthreads();
        #pragma unroll
        for (int kk16 = 0; kk16 < 16; ++kk16){
            int kk = q * 16 + kk16;
            float4 a0 = ((float4*)hsT[kk])[tg*2];
            float4 a1 = ((float4*)hsT[kk])[tg*2+1];
            float4 wv = ((float4*)wgs[kk])[cg];
            float av[8] = {a0.x,a0.y,a0.z,a0.w,a1.x,a1.y,a1.z,a1.w};
            float wj[4] = {wv.x,wv.y,wv.z,wv.w};
            #pragma unroll
            for (int i=0;i<8;++i){
                g_[i][0] += av[i]*wj[0]; g_[i][1] += av[i]*wj[1];
                g_[i][2] += av[i]*wj[2]; g_[i][3] += av[i]*wj[3];
            }
        }
        __syncthreads();
    }
    for (int qq = 0; qq < 4; ++qq){
        if (w == qq){
            #pragma unroll
            for (int i=0;i<8;++i){
                int tok = tg*8+i;
                #pragma unroll
                for (int j=0;j<4;++j){
                    int c = cg*4+j;
                    if (qq == 0) gacc[tok][c] = g_[i][j];
                    else gacc[tok][c] += g_[i][j];
                }
            }
        }
        __syncthreads();
    }
    {
        int tokr = tid >> 2;
        #pragma unroll
        for (int p = 0; p < 2; ++p){
            int f4 = (tid & 3) + 4*p;
            float4 v = ((const float4*)(tok_emb + (size_t)(t0 + tokr) * DSZ))[f4];
            int j = f4 * 4;
            agT[j+0][tokr] = v.x; agT[j+1][tokr] = v.y;
            agT[j+2][tokr] = v.z; agT[j+3][tokr] = v.w;
        }
        int c = tid & 31, tok8 = (tid >> 5) * 8;
        float bgc = bg[c];
        #pragma unroll
        for (int i=0;i<8;++i){
            int tok = tok8 + i;
            agT[32 + c][tok] = gelu_f(gacc[tok][c] + bgc);
        }
        int row = tid >> 2;
        #pragma unroll
        for (int p = 0; p < 4; ++p){
            int f4 = (tid & 3) + 4*p;
            ((float4*)wfs[row])[f4] = ((const float4*)(Wf + (size_t)row * FMZ))[f4];
        }
    }
    __syncthreads();
    {
        int tok = tid & 63, fq = tid >> 6;
        float u_[16];
        #pragma unroll
        for (int i=0;i<16;++i) u_[i]=0.f;
        for (int j = 0; j < 64; ++j){
            float a = agT[j][tok];
            float wv[16];
            *(float4*)&wv[0]  = ((float4*)wfs[j])[fq*4+0];
            *(float4*)&wv[4]  = ((float4*)wfs[j])[fq*4+1];
            *(float4*)&wv[8]  = ((float4*)wfs[j])[fq*4+2];
            *(float4*)&wv[12] = ((float4*)wfs[j])[fq*4+3];
            #pragma unroll
            for (int i=0;i<16;++i) u_[i] += a * wv[i];
        }
        #pragma unroll
        for (int i=0;i<16;++i){
            int f = fq*16+i;
            uT[f][tok] = gelu_f(u_[i] + bfv[f]);
        }
    }
    __syncthreads();
    {
        int tok = tid & 63, e = tid >> 6;
        float lt = 0.f;
        #pragma unroll 8
        for (int f = 0; f < 64; ++f) lt += uT[f][tok] * wrs[f][e];
        logit_s[tok][e] = lt + br[e];
    }
    __syncthreads();
    int my_e = 0, my_pos = 0;
    if (tid < 64){
        int tok = tid;
        float l0 = logit_s[tok][0], l1 = logit_s[tok][1];
        float l2 = logit_s[tok][2], l3 = logit_s[tok][3];
        float mx = fmaxf(fmaxf(l0,l1), fmaxf(l2,l3));
        float p0 = expf(l0-mx), p1 = expf(l1-mx), p2 = expf(l2-mx), p3 = expf(l3-mx);
        float inv = 1.0f / (p0+p1+p2+p3);
        int be = 0; float bp = p0;
        if (p1 > bp){ bp = p1; be = 1; }
        if (p2 > bp){ bp = p2; be = 2; }
        if (p3 > bp){ bp = p3; be = 3; }
        tprob[t0 + tok] = bp * inv;
        prob_s[tok][0] = p0*inv; prob_s[tok][1] = p1*inv;
        prob_s[tok][2] = p2*inv; prob_s[tok][3] = p3*inv;
        my_e = be;
        my_pos = atomicAdd(&lcnt[be], 1);
    }
    __syncthreads();
    if (tid < 4) lbase[tid] = atomicAdd(&cnt[tid], lcnt[tid]);
    __syncthreads();
    if (tid < 64) list[my_e * NTOK + lbase[my_e] + my_pos] = t0 + tid;
    if (tid < 4){
        float s = 0.f;
        for (int t = 0; t < 64; ++t) s += prob_s[t][tid];
        imp_part[blockIdx.x * 4 + tid] = s;
    }

    // ---- tail pass: h -> bf16 for this block's 64 rows (h is L2/L3-warm; coalesced 512B stores)
    {
        int wv = tid >> 6, ll = tid & 63;
        for (int r = wv; r < 64; r += 4){
            const float4* src = (const float4*)(h + (size_t)(t0 + r) * HDIM);
            ushort4* dst = (ushort4*)(hbf + (size_t)(t0 + r) * HDIM);
            #pragma unroll
            for (int i = 0; i < 4; ++i){
                float4 v = src[ll + 64 * i];
                ushort4 o; o.x = f2bf(v.x); o.y = f2bf(v.y); o.z = f2bf(v.z); o.w = f2bf(v.w);
                dst[ll + 64 * i] = o;
            }
        }
    }
}

// ---------------- grouped GEMM (r11/r13 best core): 128x128, 32KB LDS, flat dispatch ----------------
// AGATHER=true: A rows gathered from token-indexed Abase via list (GEMM1; A/B-proven equal
// to packed in r6). AGATHER=false: A rows packed at pb+row (GEMM2 reading packed A1).
template<int KTD, int NT, bool PH1, int NWG, bool AGATHER>
__global__ __launch_bounds__(256) void k_gemm(
    const unsigned short* __restrict__ Abase,
    const unsigned short* __restrict__ Bbase,
    const int* __restrict__ list, const int* __restrict__ cnt_g,
    const float* __restrict__ bias,
    unsigned short* __restrict__ A1out,
    const float* __restrict__ hres,
    const float* __restrict__ tprob,
    float* __restrict__ outp)
{
    __shared__ __align__(16) unsigned short As[128 * 64];
    __shared__ __align__(16) unsigned short Bs[128 * 64];
    constexpr int GX = NT / 128;

    // m204 bijective XCD swizzle over the flat 1-D grid
    int p = blockIdx.x;
    int xcd = p & 7, pos = p >> 3;
    constexpr int Q = NWG >> 3, R = NWG & 7;
    int base = xcd < R ? xcd * (Q + 1) : R * (Q + 1) + (xcd - R) * Q;
    int fl = base + pos;
    int mt = fl / GX, nn = fl % GX;

    // active-tile prefix mapping: mt -> (expert e, packed base pb, local m-tile)
    int c0 = cnt_g[0], c1 = cnt_g[1], c2 = cnt_g[2], c3 = cnt_g[3];
    int nt0 = (c0 + 127) >> 7, nt1 = (c1 + 127) >> 7, nt2 = (c2 + 127) >> 7;
    int nt3 = (c3 + 127) >> 7;
    if (mt >= nt0 + nt1 + nt2 + nt3) return;
    int e = 0, pb = 0, mtl = mt, cnt = c0;
    if (mtl >= nt0){ mtl -= nt0; pb += c0; e = 1; cnt = c1;
        if (mtl >= nt1){ mtl -= nt1; pb += c1; e = 2; cnt = c2;
            if (mtl >= nt2){ mtl -= nt2; pb += c2; e = 3; cnt = c3; } } }
    int m0 = mtl * 128;
    int n0 = nn * 128;

    int tid = threadIdx.x, w = tid >> 6, l = tid & 63;
    int wr = w >> 1, wc = w & 1;
    const int* lrow = list + e * NTOK;

    // staging: instr i covers rows 8w+(l>>3)+32i; source chunk pre-swizzled
    int csw = ((l & 7) ^ (l >> 3)) * 8;
    const unsigned short* aptr[4];
    const unsigned short* bptr[4];
    #pragma unroll
    for (int i = 0; i < 4; ++i){
        int row = 8 * w + (l >> 3) + 32 * i;
        int ga = m0 + row; if (ga > cnt - 1) ga = cnt - 1;
        size_t arow = AGATHER ? (size_t)lrow[ga] : (size_t)(pb + ga);
        aptr[i] = Abase + arow * KTD + csw;
        bptr[i] = Bbase + ((size_t)e * NT + (n0 + row)) * KTD + csw;
    }
    f32x4 acc[4][4] = {};
    int rsw = (l & 7) << 4;
    for (int k0 = 0; k0 < KTD; k0 += 64){
        #pragma unroll
        for (int i = 0; i < 4; ++i)
            gld_lds16(aptr[i] + k0, (char*)As + w * 1024 + i * 4096);
        #pragma unroll
        for (int i = 0; i < 4; ++i)
            gld_lds16(bptr[i] + k0, (char*)Bs + w * 1024 + i * 4096);
        __syncthreads();
        #pragma unroll
        for (int kk = 0; kk < 2; ++kk){
            bf16x8 a[4], b[4];
            #pragma unroll
            for (int m = 0; m < 4; ++m)
                a[m] = *(const bf16x8*)((const char*)As + (wr*64 + m*16 + (l&15))*128 + ((kk*64 + (l>>4)*16) ^ rsw));
            #pragma unroll
            for (int n = 0; n < 4; ++n)
                b[n] = *(const bf16x8*)((const char*)Bs + (wc*64 + n*16 + (l&15))*128 + ((kk*64 + (l>>4)*16) ^ rsw));
            #pragma unroll
            for (int m = 0; m < 4; ++m)
                #pragma unroll
                for (int n = 0; n < 4; ++n)
                    acc[m][n] = __builtin_amdgcn_mfma_f32_16x16x32_bf16(a[m], b[n], acc[m][n], 0, 0, 0);
        }
        __syncthreads();
    }

    // epilogue: C/D layout col = lane&15 (+16*n), row = (lane>>4)*4 + reg (+16*m)
    float bs[4];
    #pragma unroll
    for (int n = 0; n < 4; ++n)
        bs[n] = bias[e * NT + n0 + wc * 64 + n * 16 + (l & 15)];
    #pragma unroll
    for (int m = 0; m < 4; ++m){
        #pragma unroll
        for (int r = 0; r < 4; ++r){
            int row = wr * 64 + m * 16 + (l >> 4) * 4 + r;
            int gg = m0 + row;
            if (gg < cnt){
                if (PH1){
                    #pragma unroll
                    for (int n = 0; n < 4; ++n){
                        int col = n0 + wc * 64 + n * 16 + (l & 15);
                        float v = acc[m][n][r] + bs[n];
                        A1out[(size_t)(pb + gg) * FFZ + col] = f2bf(gelu_f(v));
                    }
                } else {
                    int tok = lrow[gg];
                    float sc = 0.5f * tprob[tok];
                    #pragma unroll
                    for (int n = 0; n < 4; ++n){
                        int col = n0 + wc * 64 + n * 16 + (l & 15);
                        float v = acc[m][n][r] + bs[n];
                        size_t o = (size_t)tok * HDIM + col;
                        outp[o] = hres[o] + sc * v;
                    }
                }
            }
        }
    }
}

// ---------------- final: lb_loss ----------------
__global__ void k_final(const float* __restrict__ imp_part, const int* __restrict__ cnt,
                        float* __restrict__ outp){
    __shared__ float imp_s[4];
    int tid = threadIdx.x;
    if (tid < 4){
        float s = 0.f;
        for (int b = 0; b < 256; ++b) s += imp_part[b*4 + tid];
        imp_s[tid] = s;
    }
    __syncthreads();
    if (tid == 0){
        float lb = 0.f;
        #pragma unroll
        for (int e = 0; e < 4; ++e) lb += imp_s[e] * (float)cnt[e];
        outp[(size_t)NTOK * HDIM] = (float)NEXP * lb / ((float)NTOK * (float)NTOK + 1e-8f);
    }
}

extern "C" void kernel_launch(void* const* d_in, const int* in_sizes, int n_in,
                              void* d_out, int out_size, void* d_ws, size_t ws_size,
                              hipStream_t stream){
    const float* h       = (const float*)d_in[0];
    const float* tok_emb = (const float*)d_in[1];
    const float* ln_g = (const float*)d_in[3];
    const float* ln_b = (const float*)d_in[4];
    const float* Wg   = (const float*)d_in[5];
    const float* bg   = (const float*)d_in[6];
    const float* Wf   = (const float*)d_in[7];
    const float* bfv  = (const float*)d_in[8];
    const float* Wr   = (const float*)d_in[9];
    const float* br   = (const float*)d_in[10];
    const float* W1   = (const float*)d_in[11];
    const float* b1   = (const float*)d_in[12];
    const float* W2   = (const float*)d_in[13];
    const float* b2   = (const float*)d_in[14];
    float* outp = (float*)d_out;
    char* ws = (char*)d_ws;

    unsigned short* h_bf = (unsigned short*)(ws);               // 33554432 B  bf16(h), token order
    unsigned short* W1T  = (unsigned short*)(ws + 33554432);    // 16777216 B
    unsigned short* W2T  = (unsigned short*)(ws + 50331648);    // 16777216 B
    unsigned short* A1   = (unsigned short*)(ws + 67108864);    // 67108864 B  packed [NTOK][FFZ]
    float* tprob = (float*)(ws + 134348800);
    int*   list  = (int*)(ws + 134414336);                      // [E][NTOK]
    int*   cnt   = (int*)(ws + 134676480);                      // [E]
    float* imp   = (float*)(ws + 134676736);                    // [256][E]

    constexpr int NWG1 = (NTOK/128 + 3) * (FFZ/128);   // 2096
    constexpr int NWG2 = (NTOK/128 + 3) * (HDIM/128);  // 1048

    k_transpose2<<<dim3(64, 32, 8), dim3(32, 8), 0, stream>>>(W1, W2, W1T, W2T, cnt);
    k_route<<<NTOK/64, 256, 0, stream>>>(h, tok_emb, ln_g, ln_b, Wg, bg, Wf, bfv, Wr, br,
                                         tprob, list, cnt, imp, h_bf);
    k_gemm<HDIM, FFZ, true, NWG1, true><<<NWG1, 256, 0, stream>>>(
        h_bf, W1T, list, cnt, b1, A1, nullptr, nullptr, nullptr);
    k_gemm<FFZ, HDIM, false, NWG2, false><<<NWG2, 256, 0, stream>>>(
        A1, W2T, list, cnt, b2, nullptr, h, tprob, outp);
    k_final<<<1, 64, 0, stream>>>(imp, cnt, outp);
}

// Round 15
// 307.862 us; speedup vs baseline: 1.2648x; 1.1602x over previous
//
#include <hip/hip_runtime.h>
#include <hip/hip_bf16.h>
#include <math.h>

#define NTOK 16384
#define HDIM 1024
#define DSZ 32
#define DGZ 32
#define FMZ 64
#define NEXP 4
#define FFZ 2048

typedef __attribute__((ext_vector_type(4))) float f32x4;
typedef __attribute__((ext_vector_type(8))) short bf16x8;

__device__ __forceinline__ unsigned short f2bf(float f){
    union { float f; unsigned int u; } v; v.f = f;
    unsigned int r = (v.u + 0x7FFFu + ((v.u >> 16) & 1u)) >> 16;
    return (unsigned short)r;
}
__device__ __forceinline__ float gelu_f(float x){
    return 0.5f * x * (1.0f + erff(x * 0.70710678118654752440f));
}
__device__ __forceinline__ void gld_lds16(const void* g, void* s){
    __builtin_amdgcn_global_load_lds((const __attribute__((address_space(1))) unsigned int*)g,
                                     (__attribute__((address_space(3))) unsigned int*)s, 16, 0, 0);
}

// ---------------- kernel 1: both weight transposes in one launch (+ cnt zeroing) ----------------
__global__ __launch_bounds__(256) void k_transpose2(const float* __restrict__ W1,
        const float* __restrict__ W2, unsigned short* __restrict__ W1T,
        unsigned short* __restrict__ W2T, int* __restrict__ cnt){
    __shared__ float tile[32][33];
    if (blockIdx.x == 0 && blockIdx.y == 0 && blockIdx.z == 0 &&
        threadIdx.y == 0 && threadIdx.x < 4)
        cnt[threadIdx.x] = 0;
    int z = blockIdx.z;
    const float* in; unsigned short* out; int R, C, bx, by;
    if (z < 4){
        in = W1 + (size_t)z * HDIM * FFZ; out = W1T + (size_t)z * HDIM * FFZ;
        R = HDIM; C = FFZ; bx = blockIdx.x * 32; by = blockIdx.y * 32;
    } else {
        int e = z - 4;
        in = W2 + (size_t)e * FFZ * HDIM; out = W2T + (size_t)e * FFZ * HDIM;
        R = FFZ; C = HDIM; bx = blockIdx.y * 32; by = blockIdx.x * 32;
    }
    int x = threadIdx.x, y = threadIdx.y;
    #pragma unroll
    for (int i = 0; i < 32; i += 8)
        tile[y + i][x] = in[(size_t)(by + y + i) * C + (bx + x)];
    __syncthreads();
    #pragma unroll
    for (int i = 0; i < 32; i += 8)
        out[(size_t)(bx + y + i) * R + (by + x)] = f2bf(tile[x][y + i]);
}

// ---------------- kernel 2: fused routing (stats + route + h->bf16 conversion tail) ----------------
__global__ __launch_bounds__(256) void k_route(
    const float* __restrict__ h, const float* __restrict__ tok_emb,
    const float* __restrict__ ln_g, const float* __restrict__ ln_b,
    const float* __restrict__ Wg, const float* __restrict__ bg,
    const float* __restrict__ Wf, const float* __restrict__ bfv,
    const float* __restrict__ Wr, const float* __restrict__ br,
    float* __restrict__ tprob, int* __restrict__ list, int* __restrict__ cnt,
    float* __restrict__ imp_part, unsigned short* __restrict__ hbf)
{
    __shared__ __align__(16) char smem[62208];
    float* lgs  = (float*)(smem);
    float* lbs  = (float*)(smem + 4096);
    float (*hsT)[64]  = (float(*)[64])(smem + 8192);
    float (*wgs)[32]  = (float(*)[32])(smem + 24576);
    float (*gacc)[32] = (float(*)[32])(smem + 32768);
    float* mus = (float*)(smem + 40960);
    float* rss = (float*)(smem + 41216);
    float (*wrs)[4]     = (float(*)[4])(smem + 41472);
    float (*logit_s)[5] = (float(*)[5])(smem + 42496);
    float (*prob_s)[5]  = (float(*)[5])(smem + 43776);
    int* lcnt  = (int*)(smem + 45056);
    int* lbase = (int*)(smem + 45072);
    float (*agT)[64] = (float(*)[64])(smem);
    float (*wfs)[64] = (float(*)[64])(smem + 16384);
    float (*uT)[64]  = (float(*)[64])(smem + 45824);

    int tid = threadIdx.x;
    int t0 = blockIdx.x * 64;

    ((float4*)lgs)[tid] = ((const float4*)ln_g)[tid];
    ((float4*)lbs)[tid] = ((const float4*)ln_b)[tid];
    if (tid < 64) ((float4*)wrs)[tid] = ((const float4*)Wr)[tid];
    if (tid < 4) lcnt[tid] = 0;

    {
        int tokrow = tid >> 2, q4 = tid & 3;
        const float4* hp = (const float4*)(h + (size_t)(t0 + tokrow) * HDIM);
        float s = 0.f, s2 = 0.f;
        #pragma unroll 8
        for (int i = 0; i < 64; ++i){
            float4 v = hp[q4 + 4 * i];
            s  += v.x + v.y + v.z + v.w;
            s2 += v.x*v.x + v.y*v.y + v.z*v.z + v.w*v.w;
        }
        s  += __shfl_xor(s, 1, 64);  s2 += __shfl_xor(s2, 1, 64);
        s  += __shfl_xor(s, 2, 64);  s2 += __shfl_xor(s2, 2, 64);
        if (q4 == 0){
            float mu = s * (1.0f / HDIM);
            float var = fmaxf(s2 * (1.0f / HDIM) - mu * mu, 0.f);
            mus[tokrow] = mu;
            rss[tokrow] = 1.0f / sqrtf(var + 1e-5f);
        }
    }
    __syncthreads();

    int l = tid & 63, w = tid >> 6;
    int tg = l & 7, cg = l >> 3, q = w;
    float g_[8][4];
    #pragma unroll
    for (int i=0;i<8;++i){ g_[i][0]=0.f; g_[i][1]=0.f; g_[i][2]=0.f; g_[i][3]=0.f; }
    int tokrow = tid >> 2;
    float m_ = mus[tokrow], r_ = rss[tokrow];
    const float* hrow = h + (size_t)(t0 + tokrow) * HDIM;

    for (int k0 = 0; k0 < HDIM; k0 += 64){
        #pragma unroll
        for (int p = 0; p < 4; ++p){
            int f4 = (tid & 3) + 4 * p;
            float4 v = ((const float4*)(hrow + k0))[f4];
            int c = f4 * 4;
            hsT[c+0][tokrow] = (v.x - m_) * r_ * lgs[k0+c+0] + lbs[k0+c+0];
            hsT[c+1][tokrow] = (v.y - m_) * r_ * lgs[k0+c+1] + lbs[k0+c+1];
            hsT[c+2][tokrow] = (v.z - m_) * r_ * lgs[k0+c+2] + lbs[k0+c+2];
            hsT[c+3][tokrow] = (v.w - m_) * r_ * lgs[k0+c+3] + lbs[k0+c+3];
        }
        {
            int wgrow = tid >> 2;
            #pragma unroll
            for (int p = 0; p < 2; ++p){
                int f4 = (tid & 3) + 4 * p;
                ((float4*)wgs[wgrow])[f4] = ((const float4*)(Wg + (size_t)(k0 + wgrow) * DGZ))[f4];
            }
        }
        __syncthreads();
        #pragma unroll
        for (int kk16 = 0; kk16 < 16; ++kk16){
            int kk = q * 16 + kk16;
            float4 a0 = ((float4*)hsT[kk])[tg*2];
            float4 a1 = ((float4*)hsT[kk])[tg*2+1];
            float4 wv = ((float4*)wgs[kk])[cg];
            float av[8] = {a0.x,a0.y,a0.z,a0.w,a1.x,a1.y,a1.z,a1.w};
            float wj[4] = {wv.x,wv.y,wv.z,wv.w};
            #pragma unroll
            for (int i=0;i<8;++i){
                g_[i][0] += av[i]*wj[0]; g_[i][1] += av[i]*wj[1];
                g_[i][2] += av[i]*wj[2]; g_[i][3] += av[i]*wj[3];
            }
        }
        __syncthreads();
    }
    for (int qq = 0; qq < 4; ++qq){
        if (w == qq){
            #pragma unroll
            for (int i=0;i<8;++i){
                int tok = tg*8+i;
                #pragma unroll
                for (int j=0;j<4;++j){
                    int c = cg*4+j;
                    if (qq == 0) gacc[tok][c] = g_[i][j];
                    else gacc[tok][c] += g_[i][j];
                }
            }
        }
        __syncthreads();
    }
    {
        int tokr = tid >> 2;
        #pragma unroll
        for (int p = 0; p < 2; ++p){
            int f4 = (tid & 3) + 4*p;
            float4 v = ((const float4*)(tok_emb + (size_t)(t0 + tokr) * DSZ))[f4];
            int j = f4 * 4;
            agT[j+0][tokr] = v.x; agT[j+1][tokr] = v.y;
            agT[j+2][tokr] = v.z; agT[j+3][tokr] = v.w;
        }
        int c = tid & 31, tok8 = (tid >> 5) * 8;
        float bgc = bg[c];
        #pragma unroll
        for (int i=0;i<8;++i){
            int tok = tok8 + i;
            agT[32 + c][tok] = gelu_f(gacc[tok][c] + bgc);
        }
        int row = tid >> 2;
        #pragma unroll
        for (int p = 0; p < 4; ++p){
            int f4 = (tid & 3) + 4*p;
            ((float4*)wfs[row])[f4] = ((const float4*)(Wf + (size_t)row * FMZ))[f4];
        }
    }
    __syncthreads();
    {
        int tok = tid & 63, fq = tid >> 6;
        float u_[16];
        #pragma unroll
        for (int i=0;i<16;++i) u_[i]=0.f;
        for (int j = 0; j < 64; ++j){
            float a = agT[j][tok];
            float wv[16];
            *(float4*)&wv[0]  = ((float4*)wfs[j])[fq*4+0];
            *(float4*)&wv[4]  = ((float4*)wfs[j])[fq*4+1];
            *(float4*)&wv[8]  = ((float4*)wfs[j])[fq*4+2];
            *(float4*)&wv[12] = ((float4*)wfs[j])[fq*4+3];
            #pragma unroll
            for (int i=0;i<16;++i) u_[i] += a * wv[i];
        }
        #pragma unroll
        for (int i=0;i<16;++i){
            int f = fq*16+i;
            uT[f][tok] = gelu_f(u_[i] + bfv[f]);
        }
    }
    __syncthreads();
    {
        int tok = tid & 63, e = tid >> 6;
        float lt = 0.f;
        #pragma unroll 8
        for (int f = 0; f < 64; ++f) lt += uT[f][tok] * wrs[f][e];
        logit_s[tok][e] = lt + br[e];
    }
    __syncthreads();
    int my_e = 0, my_pos = 0;
    if (tid < 64){
        int tok = tid;
        float l0 = logit_s[tok][0], l1 = logit_s[tok][1];
        float l2 = logit_s[tok][2], l3 = logit_s[tok][3];
        float mx = fmaxf(fmaxf(l0,l1), fmaxf(l2,l3));
        float p0 = expf(l0-mx), p1 = expf(l1-mx), p2 = expf(l2-mx), p3 = expf(l3-mx);
        float inv = 1.0f / (p0+p1+p2+p3);
        int be = 0; float bp = p0;
        if (p1 > bp){ bp = p1; be = 1; }
        if (p2 > bp){ bp = p2; be = 2; }
        if (p3 > bp){ bp = p3; be = 3; }
        tprob[t0 + tok] = bp * inv;
        prob_s[tok][0] = p0*inv; prob_s[tok][1] = p1*inv;
        prob_s[tok][2] = p2*inv; prob_s[tok][3] = p3*inv;
        my_e = be;
        my_pos = atomicAdd(&lcnt[be], 1);
    }
    __syncthreads();
    if (tid < 4) lbase[tid] = atomicAdd(&cnt[tid], lcnt[tid]);
    __syncthreads();
    if (tid < 64) list[my_e * NTOK + lbase[my_e] + my_pos] = t0 + tid;
    if (tid < 4){
        float s = 0.f;
        for (int t = 0; t < 64; ++t) s += prob_s[t][tid];
        imp_part[blockIdx.x * 4 + tid] = s;
    }

    // ---- tail: h -> bf16 for this block's 64 rows (L2/L3-warm, coalesced)
    {
        int wv = tid >> 6, ll = tid & 63;
        for (int r = wv; r < 64; r += 4){
            const float4* src = (const float4*)(h + (size_t)(t0 + r) * HDIM);
            ushort4* dst = (ushort4*)(hbf + (size_t)(t0 + r) * HDIM);
            #pragma unroll
            for (int i = 0; i < 4; ++i){
                float4 v = src[ll + 64 * i];
                ushort4 o; o.x = f2bf(v.x); o.y = f2bf(v.y); o.z = f2bf(v.z); o.w = f2bf(v.w);
                dst[ll + 64 * i] = o;
            }
        }
    }
}

// ---------------- grouped GEMM v11: 128x128 tile, 8 waves x (32x64) wave-tiles ----------------
// 512 thr = 8 waves (4M x 2N); per-wave acc = 2x4 frags = 32 AGPR (halved vs 4-wave version)
// -> reg/wave ~110 on the unified file -> higher waves/CU. Same 32KB single-buffer LDS,
// plain __syncthreads() (compiler-scheduled waits), same verified 0-conflict swizzle
// (fragment row&7 == l&7, staging row&7 == (tid>>3)&7 -- both sides unchanged),
// same flat live-tile dispatch + m204 XCD swizzle. One variable changed: wave decomposition.
template<int KTD, int NT, bool PH1, int NWG, bool AGATHER>
__global__ __launch_bounds__(512) void k_gemm(
    const unsigned short* __restrict__ Abase,
    const unsigned short* __restrict__ Bbase,
    const int* __restrict__ list, const int* __restrict__ cnt_g,
    const float* __restrict__ bias,
    unsigned short* __restrict__ A1out,
    const float* __restrict__ hres,
    const float* __restrict__ tprob,
    float* __restrict__ outp)
{
    __shared__ __align__(16) unsigned short As[128 * 64];
    __shared__ __align__(16) unsigned short Bs[128 * 64];
    constexpr int GX = NT / 128;

    // m204 bijective XCD swizzle over the flat 1-D grid
    int p = blockIdx.x;
    int xcd = p & 7, pos = p >> 3;
    constexpr int Q = NWG >> 3, R = NWG & 7;
    int base = xcd < R ? xcd * (Q + 1) : R * (Q + 1) + (xcd - R) * Q;
    int fl = base + pos;
    int mt = fl / GX, nn = fl % GX;

    // active-tile prefix mapping: mt -> (expert e, packed base pb, local m-tile)
    int c0 = cnt_g[0], c1 = cnt_g[1], c2 = cnt_g[2], c3 = cnt_g[3];
    int nt0 = (c0 + 127) >> 7, nt1 = (c1 + 127) >> 7, nt2 = (c2 + 127) >> 7;
    int nt3 = (c3 + 127) >> 7;
    if (mt >= nt0 + nt1 + nt2 + nt3) return;
    int e = 0, pb = 0, mtl = mt, cnt = c0;
    if (mtl >= nt0){ mtl -= nt0; pb += c0; e = 1; cnt = c1;
        if (mtl >= nt1){ mtl -= nt1; pb += c1; e = 2; cnt = c2;
            if (mtl >= nt2){ mtl -= nt2; pb += c2; e = 3; cnt = c3; } } }
    int m0 = mtl * 128;
    int n0 = nn * 128;

    int tid = threadIdx.x, w = tid >> 6, l = tid & 63;
    int wr = w >> 1, wc = w & 1;     // 4M x 2N wave grid; wave tile 32 x 64
    const int* lrow = list + e * NTOK;

    // staging: 512 threads, 2 gld per matrix; instr i covers rows i*64 + (tid>>3)
    int srow = tid >> 3;
    int csw = ((tid & 7) ^ (srow & 7)) * 8;   // pre-swizzled source chunk
    const unsigned short* aptr[2];
    const unsigned short* bptr[2];
    #pragma unroll
    for (int i = 0; i < 2; ++i){
        int row = i * 64 + srow;
        int ga = m0 + row; if (ga > cnt - 1) ga = cnt - 1;
        size_t arow = AGATHER ? (size_t)lrow[ga] : (size_t)(pb + ga);
        aptr[i] = Abase + arow * KTD + csw;
        bptr[i] = Bbase + ((size_t)e * NT + (n0 + row)) * KTD + csw;
    }
    f32x4 acc[2][4] = {};
    int rsw = (l & 7) << 4;
    for (int k0 = 0; k0 < KTD; k0 += 64){
        gld_lds16(aptr[0] + k0, (char*)As + tid * 16);
        gld_lds16(aptr[1] + k0, (char*)As + 8192 + tid * 16);
        gld_lds16(bptr[0] + k0, (char*)Bs + tid * 16);
        gld_lds16(bptr[1] + k0, (char*)Bs + 8192 + tid * 16);
        __syncthreads();
        #pragma unroll
        for (int kk = 0; kk < 2; ++kk){
            bf16x8 a[2], b[4];
            #pragma unroll
            for (int m = 0; m < 2; ++m)
                a[m] = *(const bf16x8*)((const char*)As + (wr*32 + m*16 + (l&15))*128 + ((kk*64 + (l>>4)*16) ^ rsw));
            #pragma unroll
            for (int n = 0; n < 4; ++n)
                b[n] = *(const bf16x8*)((const char*)Bs + (wc*64 + n*16 + (l&15))*128 + ((kk*64 + (l>>4)*16) ^ rsw));
            #pragma unroll
            for (int m = 0; m < 2; ++m)
                #pragma unroll
                for (int n = 0; n < 4; ++n)
                    acc[m][n] = __builtin_amdgcn_mfma_f32_16x16x32_bf16(a[m], b[n], acc[m][n], 0, 0, 0);
        }
        __syncthreads();
    }

    // epilogue: C/D layout col = lane&15 (+16*n), row = (lane>>4)*4 + reg (+16*m)
    float bs[4];
    #pragma unroll
    for (int n = 0; n < 4; ++n)
        bs[n] = bias[e * NT + n0 + wc * 64 + n * 16 + (l & 15)];
    #pragma unroll
    for (int m = 0; m < 2; ++m){
        #pragma unroll
        for (int r = 0; r < 4; ++r){
            int row = wr * 32 + m * 16 + (l >> 4) * 4 + r;
            int gg = m0 + row;
            if (gg < cnt){
                if (PH1){
                    #pragma unroll
                    for (int n = 0; n < 4; ++n){
                        int col = n0 + wc * 64 + n * 16 + (l & 15);
                        float v = acc[m][n][r] + bs[n];
                        A1out[(size_t)(pb + gg) * FFZ + col] = f2bf(gelu_f(v));
                    }
                } else {
                    int tok = lrow[gg];
                    float sc = 0.5f * tprob[tok];
                    #pragma unroll
                    for (int n = 0; n < 4; ++n){
                        int col = n0 + wc * 64 + n * 16 + (l & 15);
                        float v = acc[m][n][r] + bs[n];
                        size_t o = (size_t)tok * HDIM + col;
                        outp[o] = hres[o] + sc * v;
                    }
                }
            }
        }
    }
}

// ---------------- final: lb_loss ----------------
__global__ void k_final(const float* __restrict__ imp_part, const int* __restrict__ cnt,
                        float* __restrict__ outp){
    __shared__ float imp_s[4];
    int tid = threadIdx.x;
    if (tid < 4){
        float s = 0.f;
        for (int b = 0; b < 256; ++b) s += imp_part[b*4 + tid];
        imp_s[tid] = s;
    }
    __syncthreads();
    if (tid == 0){
        float lb = 0.f;
        #pragma unroll
        for (int e = 0; e < 4; ++e) lb += imp_s[e] * (float)cnt[e];
        outp[(size_t)NTOK * HDIM] = (float)NEXP * lb / ((float)NTOK * (float)NTOK + 1e-8f);
    }
}

extern "C" void kernel_launch(void* const* d_in, const int* in_sizes, int n_in,
                              void* d_out, int out_size, void* d_ws, size_t ws_size,
                              hipStream_t stream){
    const float* h       = (const float*)d_in[0];
    const float* tok_emb = (const float*)d_in[1];
    const float* ln_g = (const float*)d_in[3];
    const float* ln_b = (const float*)d_in[4];
    const float* Wg   = (const float*)d_in[5];
    const float* bg   = (const float*)d_in[6];
    const float* Wf   = (const float*)d_in[7];
    const float* bfv  = (const float*)d_in[8];
    const float* Wr   = (const float*)d_in[9];
    const float* br   = (const float*)d_in[10];
    const float* W1   = (const float*)d_in[11];
    const float* b1   = (const float*)d_in[12];
    const float* W2   = (const float*)d_in[13];
    const float* b2   = (const float*)d_in[14];
    float* outp = (float*)d_out;
    char* ws = (char*)d_ws;

    unsigned short* h_bf = (unsigned short*)(ws);               // 33554432 B  bf16(h), token order
    unsigned short* W1T  = (unsigned short*)(ws + 33554432);    // 16777216 B
    unsigned short* W2T  = (unsigned short*)(ws + 50331648);    // 16777216 B
    unsigned short* A1   = (unsigned short*)(ws + 67108864);    // 67108864 B  packed [NTOK][FFZ]
    float* tprob = (float*)(ws + 134348800);
    int*   list  = (int*)(ws + 134414336);                      // [E][NTOK]
    int*   cnt   = (int*)(ws + 134676480);                      // [E]
    float* imp   = (float*)(ws + 134676736);                    // [256][E]

    constexpr int NWG1 = (NTOK/128 + 3) * (FFZ/128);   // 2096
    constexpr int NWG2 = (NTOK/128 + 3) * (HDIM/128);  // 1048

    k_transpose2<<<dim3(64, 32, 8), dim3(32, 8), 0, stream>>>(W1, W2, W1T, W2T, cnt);
    k_route<<<NTOK/64, 256, 0, stream>>>(h, tok_emb, ln_g, ln_b, Wg, bg, Wf, bfv, Wr, br,
                                         tprob, list, cnt, imp, h_bf);
    k_gemm<HDIM, FFZ, true, NWG1, true><<<NWG1, 512, 0, stream>>>(
        h_bf, W1T, list, cnt, b1, A1, nullptr, nullptr, nullptr);
    k_gemm<FFZ, HDIM, false, NWG2, false><<<NWG2, 512, 0, stream>>>(
        A1, W2T, list, cnt, b2, nullptr, h, tprob, outp);
    k_final<<<1, 64, 0, stream>>>(imp, cnt, outp);
}

// Round 16
// 298.052 us; speedup vs baseline: 1.3064x; 1.0329x over previous
//
#include <hip/hip_runtime.h>
#include <hip/hip_bf16.h>
#include <math.h>

#define NTOK 16384
#define HDIM 1024
#define DSZ 32
#define DGZ 32
#define FMZ 64
#define NEXP 4
#define FFZ 2048

typedef __attribute__((ext_vector_type(4))) float f32x4;
typedef __attribute__((ext_vector_type(8))) short bf16x8;

__device__ __forceinline__ unsigned short f2bf(float f){
    union { float f; unsigned int u; } v; v.f = f;
    unsigned int r = (v.u + 0x7FFFu + ((v.u >> 16) & 1u)) >> 16;
    return (unsigned short)r;
}
__device__ __forceinline__ float gelu_f(float x){
    return 0.5f * x * (1.0f + erff(x * 0.70710678118654752440f));
}
__device__ __forceinline__ void gld_lds16(const void* g, void* s){
    __builtin_amdgcn_global_load_lds((const __attribute__((address_space(1))) unsigned int*)g,
                                     (__attribute__((address_space(3))) unsigned int*)s, 16, 0, 0);
}

// ---------------- kernel 1: both weight transposes in one launch (+ cnt zeroing) ----------------
__global__ __launch_bounds__(256) void k_transpose2(const float* __restrict__ W1,
        const float* __restrict__ W2, unsigned short* __restrict__ W1T,
        unsigned short* __restrict__ W2T, int* __restrict__ cnt){
    __shared__ float tile[32][33];
    if (blockIdx.x == 0 && blockIdx.y == 0 && blockIdx.z == 0 &&
        threadIdx.y == 0 && threadIdx.x < 4)
        cnt[threadIdx.x] = 0;
    int z = blockIdx.z;
    const float* in; unsigned short* out; int R, C, bx, by;
    if (z < 4){
        in = W1 + (size_t)z * HDIM * FFZ; out = W1T + (size_t)z * HDIM * FFZ;
        R = HDIM; C = FFZ; bx = blockIdx.x * 32; by = blockIdx.y * 32;
    } else {
        int e = z - 4;
        in = W2 + (size_t)e * FFZ * HDIM; out = W2T + (size_t)e * FFZ * HDIM;
        R = FFZ; C = HDIM; bx = blockIdx.y * 32; by = blockIdx.x * 32;
    }
    int x = threadIdx.x, y = threadIdx.y;
    #pragma unroll
    for (int i = 0; i < 32; i += 8)
        tile[y + i][x] = in[(size_t)(by + y + i) * C + (bx + x)];
    __syncthreads();
    #pragma unroll
    for (int i = 0; i < 32; i += 8)
        out[(size_t)(bx + y + i) * R + (by + x)] = f2bf(tile[x][y + i]);
}

// ---------------- kernel 2: fused routing (stats + route + h->bf16 conversion tail) ----------------
__global__ __launch_bounds__(256) void k_route(
    const float* __restrict__ h, const float* __restrict__ tok_emb,
    const float* __restrict__ ln_g, const float* __restrict__ ln_b,
    const float* __restrict__ Wg, const float* __restrict__ bg,
    const float* __restrict__ Wf, const float* __restrict__ bfv,
    const float* __restrict__ Wr, const float* __restrict__ br,
    float* __restrict__ tprob, int* __restrict__ list, int* __restrict__ cnt,
    float* __restrict__ imp_part, unsigned short* __restrict__ hbf)
{
    __shared__ __align__(16) char smem[62208];
    float* lgs  = (float*)(smem);
    float* lbs  = (float*)(smem + 4096);
    float (*hsT)[64]  = (float(*)[64])(smem + 8192);
    float (*wgs)[32]  = (float(*)[32])(smem + 24576);
    float (*gacc)[32] = (float(*)[32])(smem + 32768);
    float* mus = (float*)(smem + 40960);
    float* rss = (float*)(smem + 41216);
    float (*wrs)[4]     = (float(*)[4])(smem + 41472);
    float (*logit_s)[5] = (float(*)[5])(smem + 42496);
    float (*prob_s)[5]  = (float(*)[5])(smem + 43776);
    int* lcnt  = (int*)(smem + 45056);
    int* lbase = (int*)(smem + 45072);
    float (*agT)[64] = (float(*)[64])(smem);
    float (*wfs)[64] = (float(*)[64])(smem + 16384);
    float (*uT)[64]  = (float(*)[64])(smem + 45824);

    int tid = threadIdx.x;
    int t0 = blockIdx.x * 64;

    ((float4*)lgs)[tid] = ((const float4*)ln_g)[tid];
    ((float4*)lbs)[tid] = ((const float4*)ln_b)[tid];
    if (tid < 64) ((float4*)wrs)[tid] = ((const float4*)Wr)[tid];
    if (tid < 4) lcnt[tid] = 0;

    {
        int tokrow = tid >> 2, q4 = tid & 3;
        const float4* hp = (const float4*)(h + (size_t)(t0 + tokrow) * HDIM);
        float s = 0.f, s2 = 0.f;
        #pragma unroll 8
        for (int i = 0; i < 64; ++i){
            float4 v = hp[q4 + 4 * i];
            s  += v.x + v.y + v.z + v.w;
            s2 += v.x*v.x + v.y*v.y + v.z*v.z + v.w*v.w;
        }
        s  += __shfl_xor(s, 1, 64);  s2 += __shfl_xor(s2, 1, 64);
        s  += __shfl_xor(s, 2, 64);  s2 += __shfl_xor(s2, 2, 64);
        if (q4 == 0){
            float mu = s * (1.0f / HDIM);
            float var = fmaxf(s2 * (1.0f / HDIM) - mu * mu, 0.f);
            mus[tokrow] = mu;
            rss[tokrow] = 1.0f / sqrtf(var + 1e-5f);
        }
    }
    __syncthreads();

    int l = tid & 63, w = tid >> 6;
    int tg = l & 7, cg = l >> 3, q = w;
    float g_[8][4];
    #pragma unroll
    for (int i=0;i<8;++i){ g_[i][0]=0.f; g_[i][1]=0.f; g_[i][2]=0.f; g_[i][3]=0.f; }
    int tokrow = tid >> 2;
    float m_ = mus[tokrow], r_ = rss[tokrow];
    const float* hrow = h + (size_t)(t0 + tokrow) * HDIM;

    for (int k0 = 0; k0 < HDIM; k0 += 64){
        #pragma unroll
        for (int p = 0; p < 4; ++p){
            int f4 = (tid & 3) + 4 * p;
            float4 v = ((const float4*)(hrow + k0))[f4];
            int c = f4 * 4;
            hsT[c+0][tokrow] = (v.x - m_) * r_ * lgs[k0+c+0] + lbs[k0+c+0];
            hsT[c+1][tokrow] = (v.y - m_) * r_ * lgs[k0+c+1] + lbs[k0+c+1];
            hsT[c+2][tokrow] = (v.z - m_) * r_ * lgs[k0+c+2] + lbs[k0+c+2];
            hsT[c+3][tokrow] = (v.w - m_) * r_ * lgs[k0+c+3] + lbs[k0+c+3];
        }
        {
            int wgrow = tid >> 2;
            #pragma unroll
            for (int p = 0; p < 2; ++p){
                int f4 = (tid & 3) + 4 * p;
                ((float4*)wgs[wgrow])[f4] = ((const float4*)(Wg + (size_t)(k0 + wgrow) * DGZ))[f4];
            }
        }
        __syncthreads();
        #pragma unroll
        for (int kk16 = 0; kk16 < 16; ++kk16){
            int kk = q * 16 + kk16;
            float4 a0 = ((float4*)hsT[kk])[tg*2];
            float4 a1 = ((float4*)hsT[kk])[tg*2+1];
            float4 wv = ((float4*)wgs[kk])[cg];
            float av[8] = {a0.x,a0.y,a0.z,a0.w,a1.x,a1.y,a1.z,a1.w};
            float wj[4] = {wv.x,wv.y,wv.z,wv.w};
            #pragma unroll
            for (int i=0;i<8;++i){
                g_[i][0] += av[i]*wj[0]; g_[i][1] += av[i]*wj[1];
                g_[i][2] += av[i]*wj[2]; g_[i][3] += av[i]*wj[3];
            }
        }
        __syncthreads();
    }
    for (int qq = 0; qq < 4; ++qq){
        if (w == qq){
            #pragma unroll
            for (int i=0;i<8;++i){
                int tok = tg*8+i;
                #pragma unroll
                for (int j=0;j<4;++j){
                    int c = cg*4+j;
                    if (qq == 0) gacc[tok][c] = g_[i][j];
                    else gacc[tok][c] += g_[i][j];
                }
            }
        }
        __syncthreads();
    }
    {
        int tokr = tid >> 2;
        #pragma unroll
        for (int p = 0; p < 2; ++p){
            int f4 = (tid & 3) + 4*p;
            float4 v = ((const float4*)(tok_emb + (size_t)(t0 + tokr) * DSZ))[f4];
            int j = f4 * 4;
            agT[j+0][tokr] = v.x; agT[j+1][tokr] = v.y;
            agT[j+2][tokr] = v.z; agT[j+3][tokr] = v.w;
        }
        int c = tid & 31, tok8 = (tid >> 5) * 8;
        float bgc = bg[c];
        #pragma unroll
        for (int i=0;i<8;++i){
            int tok = tok8 + i;
            agT[32 + c][tok] = gelu_f(gacc[tok][c] + bgc);
        }
        int row = tid >> 2;
        #pragma unroll
        for (int p = 0; p < 4; ++p){
            int f4 = (tid & 3) + 4*p;
            ((float4*)wfs[row])[f4] = ((const float4*)(Wf + (size_t)row * FMZ))[f4];
        }
    }
    __syncthreads();
    {
        int tok = tid & 63, fq = tid >> 6;
        float u_[16];
        #pragma unroll
        for (int i=0;i<16;++i) u_[i]=0.f;
        for (int j = 0; j < 64; ++j){
            float a = agT[j][tok];
            float wv[16];
            *(float4*)&wv[0]  = ((float4*)wfs[j])[fq*4+0];
            *(float4*)&wv[4]  = ((float4*)wfs[j])[fq*4+1];
            *(float4*)&wv[8]  = ((float4*)wfs[j])[fq*4+2];
            *(float4*)&wv[12] = ((float4*)wfs[j])[fq*4+3];
            #pragma unroll
            for (int i=0;i<16;++i) u_[i] += a * wv[i];
        }
        #pragma unroll
        for (int i=0;i<16;++i){
            int f = fq*16+i;
            uT[f][tok] = gelu_f(u_[i] + bfv[f]);
        }
    }
    __syncthreads();
    {
        int tok = tid & 63, e = tid >> 6;
        float lt = 0.f;
        #pragma unroll 8
        for (int f = 0; f < 64; ++f) lt += uT[f][tok] * wrs[f][e];
        logit_s[tok][e] = lt + br[e];
    }
    __syncthreads();
    int my_e = 0, my_pos = 0;
    if (tid < 64){
        int tok = tid;
        float l0 = logit_s[tok][0], l1 = logit_s[tok][1];
        float l2 = logit_s[tok][2], l3 = logit_s[tok][3];
        float mx = fmaxf(fmaxf(l0,l1), fmaxf(l2,l3));
        float p0 = expf(l0-mx), p1 = expf(l1-mx), p2 = expf(l2-mx), p3 = expf(l3-mx);
        float inv = 1.0f / (p0+p1+p2+p3);
        int be = 0; float bp = p0;
        if (p1 > bp){ bp = p1; be = 1; }
        if (p2 > bp){ bp = p2; be = 2; }
        if (p3 > bp){ bp = p3; be = 3; }
        tprob[t0 + tok] = bp * inv;
        prob_s[tok][0] = p0*inv; prob_s[tok][1] = p1*inv;
        prob_s[tok][2] = p2*inv; prob_s[tok][3] = p3*inv;
        my_e = be;
        my_pos = atomicAdd(&lcnt[be], 1);
    }
    __syncthreads();
    if (tid < 4) lbase[tid] = atomicAdd(&cnt[tid], lcnt[tid]);
    __syncthreads();
    if (tid < 64) list[my_e * NTOK + lbase[my_e] + my_pos] = t0 + tid;
    if (tid < 4){
        float s = 0.f;
        for (int t = 0; t < 64; ++t) s += prob_s[t][tid];
        imp_part[blockIdx.x * 4 + tid] = s;
    }

    // ---- tail: h -> bf16 for this block's 64 rows (L2/L3-warm, coalesced)
    {
        int wv = tid >> 6, ll = tid & 63;
        for (int r = wv; r < 64; r += 4){
            const float4* src = (const float4*)(h + (size_t)(t0 + r) * HDIM);
            ushort4* dst = (ushort4*)(hbf + (size_t)(t0 + r) * HDIM);
            #pragma unroll
            for (int i = 0; i < 4; ++i){
                float4 v = src[ll + 64 * i];
                ushort4 o; o.x = f2bf(v.x); o.y = f2bf(v.y); o.z = f2bf(v.z); o.w = f2bf(v.w);
                dst[ll + 64 * i] = o;
            }
        }
    }
}

// ---------------- grouped GEMM v12: 128x64 tile, 8 waves x (32x32) wave-tiles ----------------
// 512 thr = 8 waves (4M x 2N); per-wave acc = 2x2 frags = 16 AGPR. LDS 24KB (A 16K + B 8K)
// single-buffer, plain __syncthreads(). Halved N-tile doubles the live-block count:
// GEMM1 1056 live (4.1/CU -> wave-cap), GEMM2 528 (2.06/CU) -- the r15-proven TLP lever.
// Same verified 0-conflict swizzle (row&7 == l&7 both sides), flat live-tile dispatch,
// m204 bijective XCD swizzle (n-fastest keeps the A m-panel L2-hot across re-reads).
template<int KTD, int NT, bool PH1, int NWG, bool AGATHER>
__global__ __launch_bounds__(512) void k_gemm(
    const unsigned short* __restrict__ Abase,
    const unsigned short* __restrict__ Bbase,
    const int* __restrict__ list, const int* __restrict__ cnt_g,
    const float* __restrict__ bias,
    unsigned short* __restrict__ A1out,
    const float* __restrict__ hres,
    const float* __restrict__ tprob,
    float* __restrict__ outp)
{
    __shared__ __align__(16) unsigned short As[128 * 64];   // 16 KB
    __shared__ __align__(16) unsigned short Bs[64 * 64];    // 8 KB
    constexpr int GX = NT / 64;

    // m204 bijective XCD swizzle over the flat 1-D grid
    int p = blockIdx.x;
    int xcd = p & 7, pos = p >> 3;
    constexpr int Q = NWG >> 3, R = NWG & 7;
    int base = xcd < R ? xcd * (Q + 1) : R * (Q + 1) + (xcd - R) * Q;
    int fl = base + pos;
    int mt = fl / GX, nn = fl % GX;

    // active-tile prefix mapping: mt -> (expert e, packed base pb, local m-tile)
    int c0 = cnt_g[0], c1 = cnt_g[1], c2 = cnt_g[2], c3 = cnt_g[3];
    int nt0 = (c0 + 127) >> 7, nt1 = (c1 + 127) >> 7, nt2 = (c2 + 127) >> 7;
    int nt3 = (c3 + 127) >> 7;
    if (mt >= nt0 + nt1 + nt2 + nt3) return;
    int e = 0, pb = 0, mtl = mt, cnt = c0;
    if (mtl >= nt0){ mtl -= nt0; pb += c0; e = 1; cnt = c1;
        if (mtl >= nt1){ mtl -= nt1; pb += c1; e = 2; cnt = c2;
            if (mtl >= nt2){ mtl -= nt2; pb += c2; e = 3; cnt = c3; } } }
    int m0 = mtl * 128;
    int n0 = nn * 64;

    int tid = threadIdx.x, w = tid >> 6, l = tid & 63;
    int wr = w >> 1, wc = w & 1;     // 4M x 2N wave grid; wave tile 32 x 32
    const int* lrow = list + e * NTOK;

    // staging: A 2 instrs (rows i*64 + tid>>3), B 1 instr (rows tid>>3); pre-swizzled source
    int srow = tid >> 3;
    int csw = ((tid & 7) ^ (srow & 7)) * 8;
    const unsigned short* aptr[2];
    #pragma unroll
    for (int i = 0; i < 2; ++i){
        int row = i * 64 + srow;
        int ga = m0 + row; if (ga > cnt - 1) ga = cnt - 1;
        size_t arow = AGATHER ? (size_t)lrow[ga] : (size_t)(pb + ga);
        aptr[i] = Abase + arow * KTD + csw;
    }
    const unsigned short* bptr = Bbase + ((size_t)e * NT + (n0 + srow)) * KTD + csw;

    f32x4 acc[2][2] = {};
    int rsw = (l & 7) << 4;
    for (int k0 = 0; k0 < KTD; k0 += 64){
        gld_lds16(aptr[0] + k0, (char*)As + tid * 16);
        gld_lds16(aptr[1] + k0, (char*)As + 8192 + tid * 16);
        gld_lds16(bptr + k0,    (char*)Bs + tid * 16);
        __syncthreads();
        #pragma unroll
        for (int kk = 0; kk < 2; ++kk){
            bf16x8 a[2], b[2];
            #pragma unroll
            for (int m = 0; m < 2; ++m)
                a[m] = *(const bf16x8*)((const char*)As + (wr*32 + m*16 + (l&15))*128 + ((kk*64 + (l>>4)*16) ^ rsw));
            #pragma unroll
            for (int n = 0; n < 2; ++n)
                b[n] = *(const bf16x8*)((const char*)Bs + (wc*32 + n*16 + (l&15))*128 + ((kk*64 + (l>>4)*16) ^ rsw));
            #pragma unroll
            for (int m = 0; m < 2; ++m)
                #pragma unroll
                for (int n = 0; n < 2; ++n)
                    acc[m][n] = __builtin_amdgcn_mfma_f32_16x16x32_bf16(a[m], b[n], acc[m][n], 0, 0, 0);
        }
        __syncthreads();
    }

    // epilogue: C/D layout col = lane&15 (+16*n), row = (lane>>4)*4 + reg (+16*m)
    float bs[2];
    #pragma unroll
    for (int n = 0; n < 2; ++n)
        bs[n] = bias[e * NT + n0 + wc * 32 + n * 16 + (l & 15)];
    #pragma unroll
    for (int m = 0; m < 2; ++m){
        #pragma unroll
        for (int r = 0; r < 4; ++r){
            int row = wr * 32 + m * 16 + (l >> 4) * 4 + r;
            int gg = m0 + row;
            if (gg < cnt){
                if (PH1){
                    #pragma unroll
                    for (int n = 0; n < 2; ++n){
                        int col = n0 + wc * 32 + n * 16 + (l & 15);
                        float v = acc[m][n][r] + bs[n];
                        A1out[(size_t)(pb + gg) * FFZ + col] = f2bf(gelu_f(v));
                    }
                } else {
                    int tok = lrow[gg];
                    float sc = 0.5f * tprob[tok];
                    #pragma unroll
                    for (int n = 0; n < 2; ++n){
                        int col = n0 + wc * 32 + n * 16 + (l & 15);
                        float v = acc[m][n][r] + bs[n];
                        size_t o = (size_t)tok * HDIM + col;
                        outp[o] = hres[o] + sc * v;
                    }
                }
            }
        }
    }
}

// ---------------- final: lb_loss ----------------
__global__ void k_final(const float* __restrict__ imp_part, const int* __restrict__ cnt,
                        float* __restrict__ outp){
    __shared__ float imp_s[4];
    int tid = threadIdx.x;
    if (tid < 4){
        float s = 0.f;
        for (int b = 0; b < 256; ++b) s += imp_part[b*4 + tid];
        imp_s[tid] = s;
    }
    __syncthreads();
    if (tid == 0){
        float lb = 0.f;
        #pragma unroll
        for (int e = 0; e < 4; ++e) lb += imp_s[e] * (float)cnt[e];
        outp[(size_t)NTOK * HDIM] = (float)NEXP * lb / ((float)NTOK * (float)NTOK + 1e-8f);
    }
}

extern "C" void kernel_launch(void* const* d_in, const int* in_sizes, int n_in,
                              void* d_out, int out_size, void* d_ws, size_t ws_size,
                              hipStream_t stream){
    const float* h       = (const float*)d_in[0];
    const float* tok_emb = (const float*)d_in[1];
    const float* ln_g = (const float*)d_in[3];
    const float* ln_b = (const float*)d_in[4];
    const float* Wg   = (const float*)d_in[5];
    const float* bg   = (const float*)d_in[6];
    const float* Wf   = (const float*)d_in[7];
    const float* bfv  = (const float*)d_in[8];
    const float* Wr   = (const float*)d_in[9];
    const float* br   = (const float*)d_in[10];
    const float* W1   = (const float*)d_in[11];
    const float* b1   = (const float*)d_in[12];
    const float* W2   = (const float*)d_in[13];
    const float* b2   = (const float*)d_in[14];
    float* outp = (float*)d_out;
    char* ws = (char*)d_ws;

    unsigned short* h_bf = (unsigned short*)(ws);               // 33554432 B  bf16(h), token order
    unsigned short* W1T  = (unsigned short*)(ws + 33554432);    // 16777216 B
    unsigned short* W2T  = (unsigned short*)(ws + 50331648);    // 16777216 B
    unsigned short* A1   = (unsigned short*)(ws + 67108864);    // 67108864 B  packed [NTOK][FFZ]
    float* tprob = (float*)(ws + 134348800);
    int*   list  = (int*)(ws + 134414336);                      // [E][NTOK]
    int*   cnt   = (int*)(ws + 134676480);                      // [E]
    float* imp   = (float*)(ws + 134676736);                    // [256][E]

    constexpr int NWG1 = (NTOK/128 + 3) * (FFZ/64);    // 4192
    constexpr int NWG2 = (NTOK/128 + 3) * (HDIM/64);   // 2096

    k_transpose2<<<dim3(64, 32, 8), dim3(32, 8), 0, stream>>>(W1, W2, W1T, W2T, cnt);
    k_route<<<NTOK/64, 256, 0, stream>>>(h, tok_emb, ln_g, ln_b, Wg, bg, Wf, bfv, Wr, br,
                                         tprob, list, cnt, imp, h_bf);
    k_gemm<HDIM, FFZ, true, NWG1, true><<<NWG1, 512, 0, stream>>>(
        h_bf, W1T, list, cnt, b1, A1, nullptr, nullptr, nullptr);
    k_gemm<FFZ, HDIM, false, NWG2, false><<<NWG2, 512, 0, stream>>>(
        A1, W2T, list, cnt, b2, nullptr, h, tprob, outp);
    k_final<<<1, 64, 0, stream>>>(imp, cnt, outp);
}